// Round 6
// baseline (3256.234 us; speedup 1.0000x reference)
//
#include <hip/hip_runtime.h>
#include <float.h>

#define BQ 8
#define CHN 96
#define NP 3136
#define KNN 9
#define C2 192
#define NT 196        // 16-wide tiles along n/m
#define MCH 4         // m-chunks
#define TPC (NT/MCH)  // 49 tiles per chunk
#define NFRAG 9       // 3-way split: h0,h1,h2,m0,m1,m2,l0,l1,l2
#define NLIST 16      // partial top-9 lists per query (4 m-chunks x 4 lane-groups)

typedef __attribute__((ext_vector_type(8))) short bf16x8;
typedef __attribute__((ext_vector_type(4))) float f32x4;

__device__ inline ushort f2bf(float x) {            // round-to-nearest-even
  unsigned u = __float_as_uint(x);
  return (ushort)((u + 0x7FFFu + ((u >> 16) & 1u)) >> 16);
}
__device__ inline float bf2f(ushort h) { return __uint_as_float((unsigned)h << 16); }

__device__ inline void gl2lds16(const void* g, void* l) {
  __builtin_amdgcn_global_load_lds(
      (const __attribute__((address_space(1))) unsigned int*)g,
      (__attribute__((address_space(3))) unsigned int*)l, 16, 0, 0);
}

// stage A tile tg into lds_a buffer s (9 x 1KB segs; wave w: segs {w,w+4}, wave0 also 8)
#define STAGE_A(astb_, tg, s) do { \
    const ushort* _src = (astb_) + (size_t)(tg) * (NFRAG * 512); \
    ushort* _dst = lds_a + (s) * (NFRAG * 512); \
    gl2lds16(_src + wave * 512 + lane * 8, _dst + wave * 512); \
    gl2lds16(_src + (wave + 4) * 512 + lane * 8, _dst + (wave + 4) * 512); \
    if (wave == 0) gl2lds16(_src + 8 * 512 + lane * 8, _dst + 8 * 512); \
  } while (0)

#define MFMA_CHAIN() do { \
    acc0 = __builtin_amdgcn_mfma_f32_16x16x32_bf16(ah0, bh0, acc0, 0, 0, 0); \
    acc1 = __builtin_amdgcn_mfma_f32_16x16x32_bf16(am0, bh0, acc1, 0, 0, 0); \
    acc2 = __builtin_amdgcn_mfma_f32_16x16x32_bf16(al0, bh0, acc2, 0, 0, 0); \
    acc1 = __builtin_amdgcn_mfma_f32_16x16x32_bf16(ah0, bm0, acc1, 0, 0, 0); \
    acc2 = __builtin_amdgcn_mfma_f32_16x16x32_bf16(ah0, bl0, acc2, 0, 0, 0); \
    acc1 = __builtin_amdgcn_mfma_f32_16x16x32_bf16(am0, bm0, acc1, 0, 0, 0); \
    acc0 = __builtin_amdgcn_mfma_f32_16x16x32_bf16(ah1, bh1, acc0, 0, 0, 0); \
    acc1 = __builtin_amdgcn_mfma_f32_16x16x32_bf16(am1, bh1, acc1, 0, 0, 0); \
    acc2 = __builtin_amdgcn_mfma_f32_16x16x32_bf16(al1, bh1, acc2, 0, 0, 0); \
    acc1 = __builtin_amdgcn_mfma_f32_16x16x32_bf16(ah1, bm1, acc1, 0, 0, 0); \
    acc2 = __builtin_amdgcn_mfma_f32_16x16x32_bf16(ah1, bl1, acc2, 0, 0, 0); \
    acc1 = __builtin_amdgcn_mfma_f32_16x16x32_bf16(am1, bm1, acc1, 0, 0, 0); \
    acc0 = __builtin_amdgcn_mfma_f32_16x16x32_bf16(ah2, bh2, acc0, 0, 0, 0); \
    acc1 = __builtin_amdgcn_mfma_f32_16x16x32_bf16(am2, bh2, acc1, 0, 0, 0); \
    acc2 = __builtin_amdgcn_mfma_f32_16x16x32_bf16(al2, bh2, acc2, 0, 0, 0); \
    acc1 = __builtin_amdgcn_mfma_f32_16x16x32_bf16(ah2, bm2, acc1, 0, 0, 0); \
    acc2 = __builtin_amdgcn_mfma_f32_16x16x32_bf16(ah2, bl2, acc2, 0, 0, 0); \
    acc1 = __builtin_amdgcn_mfma_f32_16x16x32_bf16(am2, bm2, acc1, 0, 0, 0); \
  } while (0)

#define INSERT9(d, m) do { \
    if ((d) < tv[KNN - 1]) { \
      tv[8] = (d); ti[8] = (m); \
      _Pragma("unroll") \
      for (int j = 8; j > 0; --j) { \
        bool swp = tv[j] < tv[j - 1]; \
        float fa = swp ? tv[j] : tv[j - 1]; \
        float fb = swp ? tv[j - 1] : tv[j]; \
        int ia = swp ? ti[j] : ti[j - 1]; \
        int ib = swp ? ti[j - 1] : ti[j]; \
        tv[j - 1] = fa; tv[j] = fb; ti[j - 1] = ia; ti[j] = ib; \
      } \
    } \
  } while (0)

// ---------- K1: h[b][o][n] = sum_c fc1_w[o][c] * x[b][c][n] + fc1_b[o]
__global__ __launch_bounds__(256) void k1_conv1(const float* __restrict__ x,
    const float* __restrict__ w, const float* __restrict__ bias, float* __restrict__ h) {
  __shared__ float sw[CHN * CHN];
  __shared__ float sx[CHN][64];
  int b = blockIdx.y;
  int n0 = blockIdx.x * 64;
  int tid = threadIdx.x;
  for (int i = tid; i < CHN * CHN; i += 256) sw[i] = w[i];
  const float* xb = x + (size_t)b * CHN * NP + n0;
  for (int i = tid; i < CHN * 64; i += 256) {
    int c = i >> 6, nn = i & 63;
    sx[c][nn] = xb[(size_t)c * NP + nn];
  }
  __syncthreads();
  int nn = tid & 63;
  int o0 = (tid >> 6) * 24;
  float acc[24];
#pragma unroll
  for (int j = 0; j < 24; ++j) acc[j] = 0.f;
  for (int c = 0; c < CHN; ++c) {
    float xv = sx[c][nn];
#pragma unroll
    for (int j = 0; j < 24; ++j) acc[j] = fmaf(sw[(o0 + j) * CHN + c], xv, acc[j]);
  }
  float* hb = h + (size_t)b * CHN * NP + n0;
#pragma unroll
  for (int j = 0; j < 24; ++j) hb[(size_t)(o0 + j) * NP + nn] = acc[j] + bias[o0 + j];
}

// ---------- K2/K7: per-(b,channel) mean + rstd
__global__ __launch_bounds__(256) void k2_stats(const float* __restrict__ src,
                                                float* __restrict__ stat) {
  int bo = blockIdx.x;
  const float* p = src + (size_t)bo * NP;
  float s = 0.f, ss = 0.f;
  for (int i = threadIdx.x; i < NP; i += 256) { float v = p[i]; s += v; ss = fmaf(v, v, ss); }
#pragma unroll
  for (int off = 32; off; off >>= 1) { s += __shfl_down(s, off); ss += __shfl_down(ss, off); }
  __shared__ float as[4], ass[4];
  int wv = threadIdx.x >> 6;
  if ((threadIdx.x & 63) == 0) { as[wv] = s; ass[wv] = ss; }
  __syncthreads();
  if (threadIdx.x == 0) {
    float S = as[0] + as[1] + as[2] + as[3];
    float SS = ass[0] + ass[1] + ass[2] + ass[3];
    float mean = S * (1.f / NP);
    float var = SS * (1.f / NP) - mean * mean;
    if (var < 0.f) var = 0.f;
    stat[bo * 2] = mean;
    stat[bo * 2 + 1] = 1.f / sqrtf(var + 1e-5f);
  }
}

// ---------- K3: normalize h -> feats[b][n][c]; nrm = feats/max(||f||,eps); sq = sum(nrm^2)
__global__ __launch_bounds__(256) void k3_norm(const float* __restrict__ h,
    const float* __restrict__ stat, float* __restrict__ feats, float* __restrict__ nrm,
    float* __restrict__ sq) {
  __shared__ float tile[CHN][33];
  __shared__ float part[8][32];
  __shared__ float sinv[32];
  int b = blockIdx.y, n0 = blockIdx.x * 32;
  int tid = threadIdx.x;
  for (int i = tid; i < CHN * 32; i += 256) {
    int c = i >> 5, nn = i & 31;
    float m = stat[(b * CHN + c) * 2];
    float r = stat[(b * CHN + c) * 2 + 1];
    tile[c][nn] = (h[((size_t)(b * CHN + c)) * NP + n0 + nn] - m) * r;
  }
  __syncthreads();
  int nn = tid & 31, sub = tid >> 5;
  float ss = 0.f;
#pragma unroll
  for (int j = 0; j < 12; ++j) { float f = tile[sub * 12 + j][nn]; ss = fmaf(f, f, ss); }
  part[sub][nn] = ss;
  __syncthreads();
  if (tid < 32) {
    float S = 0.f;
#pragma unroll
    for (int w = 0; w < 8; ++w) S += part[w][tid];
    float norm = sqrtf(S);
    sinv[tid] = 1.f / fmaxf(norm, 1e-12f);
  }
  __syncthreads();
  float inv = sinv[nn];
  float ss2 = 0.f;
#pragma unroll
  for (int j = 0; j < 12; ++j) { float f = tile[sub * 12 + j][nn] * inv; ss2 = fmaf(f, f, ss2); }
  part[sub][nn] = ss2;
  __syncthreads();
  if (tid < 32) {
    float S = 0.f;
#pragma unroll
    for (int w = 0; w < 8; ++w) S += part[w][tid];
    sq[(size_t)b * NP + n0 + tid] = S;
  }
  for (int i = tid; i < 32 * CHN; i += 256) {
    int nn2 = i / CHN, c = i - nn2 * CHN;
    float f = tile[c][nn2];
    size_t o = ((size_t)b * NP + n0 + nn2) * CHN + c;
    feats[o] = f;
    nrm[o] = f * sinv[nn2];
  }
}

// ---------- K3b: build MFMA operand streams, 3-way bf16 split
__global__ __launch_bounds__(256) void k3b_prep(const float* __restrict__ nrm,
    ushort* __restrict__ ast, ushort* __restrict__ bst) {
  int b = blockIdx.y, t = blockIdx.x;
  int tid = threadIdx.x;
  const float* nb = nrm + (size_t)b * NP * CHN;
  ushort* ao = ast + (((size_t)b * NT + t) * NFRAG) * 512;
  for (int e = tid; e < NFRAG * 512; e += 256) {
    int f = e >> 9, l = (e >> 3) & 63, j = e & 7;
    int part = f / 3, sl = f - part * 3;
    int c = sl * 32 + (l >> 4) * 8 + j;
    int m = t * 16 + (l & 15);
    float xv = nb[(size_t)m * CHN + c];
    ushort hh = f2bf(xv);
    float rm = xv - bf2f(hh);          // exact
    ushort md = f2bf(rm);
    ushort v = (part == 0) ? hh : (part == 1) ? md : f2bf(rm - bf2f(md));
    ao[e] = v;
  }
  ushort* bo = bst + (((size_t)b * NT + t) * NFRAG) * 512;
  for (int e = tid; e < NFRAG * 512; e += 256) {
    int f = e >> 9, l = (e >> 3) & 63, j = e & 7;
    int part = f / 3, sl = f - part * 3;
    int c = sl * 32 + (l >> 4) * 8 + j;
    int n = t * 16 + (l & 15);
    float y = -2.f * nb[(size_t)n * CHN + c];
    ushort hh = f2bf(y);
    float rm = y - bf2f(hh);
    ushort md = f2bf(rm);
    ushort v = (part == 0) ? hh : (part == 1) ? md : f2bf(rm - bf2f(md));
    bo[e] = v;
  }
}

// ---------- K4 (REAL, unchanged from round 5): MFMA key + top-9
__global__ __launch_bounds__(256, 2) void k4_mfma(
    const ushort* __restrict__ ast, const ushort* __restrict__ bst,
    const float* __restrict__ sq, float* __restrict__ pd, int* __restrict__ pi) {
  int b = blockIdx.z, chunk = blockIdx.y, ng = blockIdx.x;
  int wave = threadIdx.x >> 6, lane = threadIdx.x & 63;
  int tn = ng * 4 + wave;
  const bf16x8* bp = (const bf16x8*)(bst + (((size_t)b * NT + tn) * NFRAG) * 512);
  bf16x8 bh0 = bp[0 * 64 + lane], bh1 = bp[1 * 64 + lane], bh2 = bp[2 * 64 + lane];
  bf16x8 bm0 = bp[3 * 64 + lane], bm1 = bp[4 * 64 + lane], bm2 = bp[5 * 64 + lane];
  bf16x8 bl0 = bp[6 * 64 + lane], bl1 = bp[7 * 64 + lane], bl2 = bp[8 * 64 + lane];
  const float* sqb = sq + (size_t)b * NP;
  __shared__ ushort lds_a[2 * NFRAG * 512];
  const ushort* astb = ast + ((size_t)b * NT) * (NFRAG * 512);
  int t0 = chunk * TPC;
  STAGE_A(astb, t0, 0);
  __syncthreads();
  float tv[KNN]; int ti[KNN];
#pragma unroll
  for (int i = 0; i < KNN; ++i) { tv[i] = FLT_MAX; ti[i] = 0x7fffffff; }
  for (int tl = 0; tl < TPC; ++tl) {
    int cur = tl & 1;
    if (tl + 1 < TPC) STAGE_A(astb, t0 + tl + 1, cur ^ 1);
    int mbase = (t0 + tl) * 16 + ((lane >> 4) << 2);
    float4 sqv = *(const float4*)(sqb + mbase);
    const bf16x8* ap = (const bf16x8*)(lds_a + (size_t)cur * (NFRAG * 512));
    bf16x8 ah0 = ap[0 * 64 + lane], ah1 = ap[1 * 64 + lane], ah2 = ap[2 * 64 + lane];
    bf16x8 am0 = ap[3 * 64 + lane], am1 = ap[4 * 64 + lane], am2 = ap[5 * 64 + lane];
    bf16x8 al0 = ap[6 * 64 + lane], al1 = ap[7 * 64 + lane], al2 = ap[8 * 64 + lane];
    f32x4 acc0 = {0.f, 0.f, 0.f, 0.f}, acc1 = {0.f, 0.f, 0.f, 0.f}, acc2 = {0.f, 0.f, 0.f, 0.f};
    MFMA_CHAIN();
#pragma unroll
    for (int r = 0; r < 4; ++r) {
      float d = ((acc1[r] + acc2[r]) + acc0[r]) + sqv[r];
      INSERT9(d, mbase + r);
    }
    __syncthreads();
  }
  int g = lane >> 4;
  int n = tn * 16 + (lane & 15);
  size_t base = (((size_t)b * NLIST + (chunk * 4 + g)) * NP + n) * (size_t)KNN;
#pragma unroll
  for (int i = 0; i < KNN; ++i) { pd[base + i] = tv[i]; pi[base + i] = ti[i]; }
}

// ---------- PROBE VB: B fragments in LDS (low reg pressure), plain launch_bounds
__global__ __launch_bounds__(256) void k4_vb(
    const ushort* __restrict__ ast, const ushort* __restrict__ bst,
    const float* __restrict__ sq, float* __restrict__ pd, int* __restrict__ pi) {
  int b = blockIdx.z, chunk = blockIdx.y, ng = blockIdx.x;
  int wave = threadIdx.x >> 6, lane = threadIdx.x & 63;
  int tn = ng * 4 + wave;
  __shared__ ushort lds_a[2 * NFRAG * 512];
  __shared__ ushort lds_b[4 * NFRAG * 512];
  ushort* smB = lds_b + wave * (NFRAG * 512);
  const ushort* bpu = bst + (((size_t)b * NT + tn) * NFRAG) * 512;
#pragma unroll
  for (int f = 0; f < NFRAG; ++f) gl2lds16(bpu + f * 512 + lane * 8, smB + f * 512);
  const float* sqb = sq + (size_t)b * NP;
  const ushort* astb = ast + ((size_t)b * NT) * (NFRAG * 512);
  int t0 = chunk * TPC;
  STAGE_A(astb, t0, 0);
  __syncthreads();
  float tv[KNN]; int ti[KNN];
#pragma unroll
  for (int i = 0; i < KNN; ++i) { tv[i] = FLT_MAX; ti[i] = 0x7fffffff; }
  const bf16x8* bpl = (const bf16x8*)smB;
  for (int tl = 0; tl < TPC; ++tl) {
    int cur = tl & 1;
    if (tl + 1 < TPC) STAGE_A(astb, t0 + tl + 1, cur ^ 1);
    int mbase = (t0 + tl) * 16 + ((lane >> 4) << 2);
    float4 sqv = *(const float4*)(sqb + mbase);
    const bf16x8* ap = (const bf16x8*)(lds_a + (size_t)cur * (NFRAG * 512));
    bf16x8 ah0 = ap[0 * 64 + lane], ah1 = ap[1 * 64 + lane], ah2 = ap[2 * 64 + lane];
    bf16x8 am0 = ap[3 * 64 + lane], am1 = ap[4 * 64 + lane], am2 = ap[5 * 64 + lane];
    bf16x8 al0 = ap[6 * 64 + lane], al1 = ap[7 * 64 + lane], al2 = ap[8 * 64 + lane];
    bf16x8 bh0 = bpl[0 * 64 + lane], bh1 = bpl[1 * 64 + lane], bh2 = bpl[2 * 64 + lane];
    bf16x8 bm0 = bpl[3 * 64 + lane], bm1 = bpl[4 * 64 + lane], bm2 = bpl[5 * 64 + lane];
    bf16x8 bl0 = bpl[6 * 64 + lane], bl1 = bpl[7 * 64 + lane], bl2 = bpl[8 * 64 + lane];
    f32x4 acc0 = {0.f, 0.f, 0.f, 0.f}, acc1 = {0.f, 0.f, 0.f, 0.f}, acc2 = {0.f, 0.f, 0.f, 0.f};
    MFMA_CHAIN();
#pragma unroll
    for (int r = 0; r < 4; ++r) {
      float d = ((acc1[r] + acc2[r]) + acc0[r]) + sqv[r];
      INSERT9(d, mbase + r);
    }
    __syncthreads();
  }
  int g = lane >> 4;
  int n = tn * 16 + (lane & 15);
  size_t base = (((size_t)b * NLIST + (chunk * 4 + g)) * NP + n) * (size_t)KNN;
#pragma unroll
  for (int i = 0; i < KNN; ++i) { pd[base + i] = tv[i]; pi[base + i] = ti[i]; }
}

// ---------- PROBE VC: no insert-sort (fmin fold) — isolates insert cost
__global__ __launch_bounds__(256, 2) void k4_vc(
    const ushort* __restrict__ ast, const ushort* __restrict__ bst,
    const float* __restrict__ sq, float* __restrict__ pd) {
  int b = blockIdx.z, chunk = blockIdx.y, ng = blockIdx.x;
  int wave = threadIdx.x >> 6, lane = threadIdx.x & 63;
  int tn = ng * 4 + wave;
  const bf16x8* bp = (const bf16x8*)(bst + (((size_t)b * NT + tn) * NFRAG) * 512);
  bf16x8 bh0 = bp[0 * 64 + lane], bh1 = bp[1 * 64 + lane], bh2 = bp[2 * 64 + lane];
  bf16x8 bm0 = bp[3 * 64 + lane], bm1 = bp[4 * 64 + lane], bm2 = bp[5 * 64 + lane];
  bf16x8 bl0 = bp[6 * 64 + lane], bl1 = bp[7 * 64 + lane], bl2 = bp[8 * 64 + lane];
  const float* sqb = sq + (size_t)b * NP;
  __shared__ ushort lds_a[2 * NFRAG * 512];
  const ushort* astb = ast + ((size_t)b * NT) * (NFRAG * 512);
  int t0 = chunk * TPC;
  STAGE_A(astb, t0, 0);
  __syncthreads();
  float dmin = FLT_MAX;
  for (int tl = 0; tl < TPC; ++tl) {
    int cur = tl & 1;
    if (tl + 1 < TPC) STAGE_A(astb, t0 + tl + 1, cur ^ 1);
    int mbase = (t0 + tl) * 16 + ((lane >> 4) << 2);
    float4 sqv = *(const float4*)(sqb + mbase);
    const bf16x8* ap = (const bf16x8*)(lds_a + (size_t)cur * (NFRAG * 512));
    bf16x8 ah0 = ap[0 * 64 + lane], ah1 = ap[1 * 64 + lane], ah2 = ap[2 * 64 + lane];
    bf16x8 am0 = ap[3 * 64 + lane], am1 = ap[4 * 64 + lane], am2 = ap[5 * 64 + lane];
    bf16x8 al0 = ap[6 * 64 + lane], al1 = ap[7 * 64 + lane], al2 = ap[8 * 64 + lane];
    f32x4 acc0 = {0.f, 0.f, 0.f, 0.f}, acc1 = {0.f, 0.f, 0.f, 0.f}, acc2 = {0.f, 0.f, 0.f, 0.f};
    MFMA_CHAIN();
#pragma unroll
    for (int r = 0; r < 4; ++r) {
      float d = ((acc1[r] + acc2[r]) + acc0[r]) + sqv[r];
      dmin = fminf(dmin, d);
    }
    __syncthreads();
  }
  size_t slot = (((size_t)(b * MCH + chunk) * (NT / 4) + ng) * 256 + threadIdx.x);
  pd[slot] = dmin;
}

// ---------- PROBE VD: no MFMA (synthetic d) — isolates stage+barrier+insert skeleton
__global__ __launch_bounds__(256, 2) void k4_vd(
    const ushort* __restrict__ ast, float* __restrict__ pd, int* __restrict__ pi) {
  int b = blockIdx.z, chunk = blockIdx.y, ng = blockIdx.x;
  int wave = threadIdx.x >> 6, lane = threadIdx.x & 63;
  __shared__ ushort lds_a[2 * NFRAG * 512];
  const ushort* astb = ast + ((size_t)b * NT) * (NFRAG * 512);
  int t0 = chunk * TPC;
  STAGE_A(astb, t0, 0);
  __syncthreads();
  float tv[KNN]; int ti[KNN];
#pragma unroll
  for (int i = 0; i < KNN; ++i) { tv[i] = FLT_MAX; ti[i] = 0x7fffffff; }
  for (int tl = 0; tl < TPC; ++tl) {
    int cur = tl & 1;
    if (tl + 1 < TPC) STAGE_A(astb, t0 + tl + 1, cur ^ 1);
    const bf16x8* ap = (const bf16x8*)(lds_a + (size_t)cur * (NFRAG * 512));
    float fold = 0.f;
#pragma unroll
    for (int f = 0; f < NFRAG; ++f) fold += (float)ap[f * 64 + lane][0];
    int mbase = (t0 + tl) * 16 + ((lane >> 4) << 2);
#pragma unroll
    for (int r = 0; r < 4; ++r) {
      unsigned hsh = ((unsigned)(t0 + tl) * 2654435761u + (unsigned)r * 40503u +
                      (unsigned)lane * 7919u) & 0xFFFFu;
      float d = fmaf(fold, 1e-30f, (float)hsh);
      INSERT9(d, mbase + r);
    }
    __syncthreads();
  }
  int g = lane >> 4;
  int n = (ng * 4 + wave) * 16 + (lane & 15);
  size_t base = (((size_t)b * NLIST + (chunk * 4 + g)) * NP + n) * (size_t)KNN;
#pragma unroll
  for (int i = 0; i < KNN; ++i) { pd[base + i] = tv[i]; pi[base + i] = ti[i]; }
}

// ---------- PROBE VE: no LDS / no barriers — A,B straight from global (L2/L3-resident)
__global__ __launch_bounds__(256) void k4_ve(
    const ushort* __restrict__ ast, const ushort* __restrict__ bst,
    const float* __restrict__ sq, float* __restrict__ pd, int* __restrict__ pi) {
  int b = blockIdx.z, chunk = blockIdx.y, ng = blockIdx.x;
  int wave = threadIdx.x >> 6, lane = threadIdx.x & 63;
  int tn = ng * 4 + wave;
  const bf16x8* bp = (const bf16x8*)(bst + (((size_t)b * NT + tn) * NFRAG) * 512);
  bf16x8 bh0 = bp[0 * 64 + lane], bh1 = bp[1 * 64 + lane], bh2 = bp[2 * 64 + lane];
  bf16x8 bm0 = bp[3 * 64 + lane], bm1 = bp[4 * 64 + lane], bm2 = bp[5 * 64 + lane];
  bf16x8 bl0 = bp[6 * 64 + lane], bl1 = bp[7 * 64 + lane], bl2 = bp[8 * 64 + lane];
  const float* sqb = sq + (size_t)b * NP;
  const ushort* astb = ast + ((size_t)b * NT) * (NFRAG * 512);
  int t0 = chunk * TPC;
  float tv[KNN]; int ti[KNN];
#pragma unroll
  for (int i = 0; i < KNN; ++i) { tv[i] = FLT_MAX; ti[i] = 0x7fffffff; }
  for (int tl = 0; tl < TPC; ++tl) {
    const bf16x8* ap = (const bf16x8*)(astb + (size_t)(t0 + tl) * (NFRAG * 512));
    int mbase = (t0 + tl) * 16 + ((lane >> 4) << 2);
    float4 sqv = *(const float4*)(sqb + mbase);
    bf16x8 ah0 = ap[0 * 64 + lane], ah1 = ap[1 * 64 + lane], ah2 = ap[2 * 64 + lane];
    bf16x8 am0 = ap[3 * 64 + lane], am1 = ap[4 * 64 + lane], am2 = ap[5 * 64 + lane];
    bf16x8 al0 = ap[6 * 64 + lane], al1 = ap[7 * 64 + lane], al2 = ap[8 * 64 + lane];
    f32x4 acc0 = {0.f, 0.f, 0.f, 0.f}, acc1 = {0.f, 0.f, 0.f, 0.f}, acc2 = {0.f, 0.f, 0.f, 0.f};
    MFMA_CHAIN();
#pragma unroll
    for (int r = 0; r < 4; ++r) {
      float d = ((acc1[r] + acc2[r]) + acc0[r]) + sqv[r];
      INSERT9(d, mbase + r);
    }
  }
  int g = lane >> 4;
  int n = tn * 16 + (lane & 15);
  size_t base = (((size_t)b * NLIST + (chunk * 4 + g)) * NP + n) * (size_t)KNN;
#pragma unroll
  for (int i = 0; i < KNN; ++i) { pd[base + i] = tv[i]; pi[base + i] = ti[i]; }
}

// ---------- K4b: merge 16 sorted top-9 lists per query
__global__ __launch_bounds__(64) void k4b_merge(const float* __restrict__ pd,
    const int* __restrict__ pi, int* __restrict__ nidx) {
  __shared__ float  sd[64][NLIST * KNN + 1];
  __shared__ ushort si[64][NLIST * KNN + 1];
  int tid = threadIdx.x;
  int q = blockIdx.x * 64 + tid;
  int b = q / NP, n = q - b * NP;
  for (int ch = 0; ch < NLIST; ++ch) {
    size_t base = (((size_t)b * NLIST + ch) * NP + n) * (size_t)KNN;
#pragma unroll
    for (int k = 0; k < KNN; ++k) {
      sd[tid][ch * KNN + k] = pd[base + k];
      si[tid][ch * KNN + k] = (ushort)pi[base + k];
    }
  }
  float dl = -FLT_MAX; int il = -1;
  int* op = nidx + (size_t)q * KNN;
  for (int k = 0; k < KNN; ++k) {
    float bd = FLT_MAX; int bi = 0x7fffffff;
    for (int j = 0; j < NLIST * KNN; ++j) {
      float d = sd[tid][j]; int i = (int)si[tid][j];
      bool gt = (d > dl) || ((d == dl) && (i > il));
      bool lt = (d < bd) || ((d == bd) && (i < bi));
      if (gt && lt) { bd = d; bi = i; }
    }
    op[k] = bi; dl = bd; il = bi;
  }
}

// ---------- K5: a = (W1-W2)·f + gb ; u = W2·f
__global__ __launch_bounds__(256) void k5_au(const float* __restrict__ feats,
    const float* __restrict__ gw, const float* __restrict__ gb,
    float* __restrict__ a, float* __restrict__ u) {
  __shared__ float sf[32][97];
  __shared__ float swc[64 * C2];
  int b = blockIdx.y, n0 = blockIdx.x * 32;
  int tid = threadIdx.x;
  for (int i = tid; i < 32 * CHN; i += 256) {
    int nn = i / CHN, c = i - nn * CHN;
    sf[nn][c] = feats[((size_t)b * NP + n0 + nn) * CHN + c];
  }
  int nn = tid & 31, sub = tid >> 5;
  for (int oc = 0; oc < 3; ++oc) {
    __syncthreads();
    for (int i = tid; i < 64 * C2; i += 256) swc[i] = gw[(size_t)(oc * 64) * C2 + i];
    __syncthreads();
    float accA[8], accU[8];
#pragma unroll
    for (int j = 0; j < 8; ++j) { accA[j] = 0.f; accU[j] = 0.f; }
    for (int c = 0; c < CHN; ++c) {
      float f = sf[nn][c];
#pragma unroll
      for (int j = 0; j < 8; ++j) {
        float w1 = swc[(sub * 8 + j) * C2 + c];
        float wv2 = swc[(sub * 8 + j) * C2 + 96 + c];
        accA[j] = fmaf(w1 - wv2, f, accA[j]);
        accU[j] = fmaf(wv2, f, accU[j]);
      }
    }
    size_t row = ((size_t)b * NP + n0 + nn) * C2;
#pragma unroll
    for (int j = 0; j < 8; ++j) {
      int o = oc * 64 + sub * 8 + j;
      a[row + o] = accA[j] + gb[o];
      u[row + o] = accU[j];
    }
  }
}

// ---------- K6: agg = relu(a + max_k u[idx_k]); ol = fc2_w·agg + fc2_b
__global__ __launch_bounds__(256) void k6_edge(const float* __restrict__ a,
    const float* __restrict__ u, const int* __restrict__ nidx,
    const float* __restrict__ w2, const float* __restrict__ b2, float* __restrict__ ol) {
  __shared__ float sagg[32][193];
  int b = blockIdx.y, n0 = blockIdx.x * 32;
  int tid = threadIdx.x;
  int wv = tid >> 6, ln = tid & 63;
  for (int p = 0; p < 8; ++p) {
    int nn = wv * 8 + p;
    size_t row = (size_t)b * NP + n0 + nn;
    const int* ip = nidx + row * KNN;
    int idx[KNN];
#pragma unroll
    for (int k = 0; k < KNN; ++k) idx[k] = ip[k];
#pragma unroll
    for (int oo = 0; oo < 3; ++oo) {
      int o = oo * 64 + ln;
      float umax = -FLT_MAX;
#pragma unroll
      for (int k = 0; k < KNN; ++k)
        umax = fmaxf(umax, u[((size_t)b * NP + idx[k]) * C2 + o]);
      float av = a[row * C2 + o];
      sagg[nn][o] = fmaxf(av + umax, 0.f);
    }
  }
  __syncthreads();
  int nn = tid & 31, sub = tid >> 5;
  for (int j = 0; j < 12; ++j) {
    int o2 = sub + 8 * j;
    float acc = b2[o2];
    for (int o = 0; o < C2; ++o) acc = fmaf(w2[o2 * C2 + o], sagg[nn][o], acc);
    ol[((size_t)b * CHN + o2) * NP + n0 + nn] = acc;
  }
}

// ---------- K8: out = (ol - mean)*rstd + shortcut
__global__ __launch_bounds__(256) void k8_final(const float* __restrict__ ol,
    const float* __restrict__ stat, const float* __restrict__ x, float* __restrict__ out) {
  int i = blockIdx.x * 256 + threadIdx.x;
  int bo = i / NP;
  float m = stat[bo * 2], r = stat[bo * 2 + 1];
  out[i] = fmaf(ol[i] - m, r, x[i]);
}

extern "C" void kernel_launch(void* const* d_in, const int* in_sizes, int n_in,
                              void* d_out, int out_size, void* d_ws, size_t ws_size,
                              hipStream_t stream) {
  const float* x   = (const float*)d_in[0];
  const float* f1w = (const float*)d_in[1];
  const float* f1b = (const float*)d_in[2];
  const float* gw  = (const float*)d_in[3];
  const float* gb  = (const float*)d_in[4];
  const float* f2w = (const float*)d_in[5];
  const float* f2b = (const float*)d_in[6];
  float* out = (float*)d_out;
  char* ws = (char*)d_ws;

  constexpr size_t SZ_MAT = (size_t)BQ * CHN * NP * 4;           // 9,633,792
  constexpr size_t SZ_STR = (size_t)BQ * NT * NFRAG * 512 * 2;   // 14,450,688
  constexpr size_t SZ_PL  = (size_t)BQ * NLIST * NP * KNN * 4;   // 14,450,688
  constexpr size_t OFF_H   = 0;
  constexpr size_t OFF_PD  = 0;
  constexpr size_t OFF_PI  = OFF_PD + SZ_PL;
  constexpr size_t OFF_A   = 0;
  constexpr size_t OFF_AST = 2 * SZ_PL;
  constexpr size_t OFF_BST = OFF_AST + SZ_STR;
  constexpr size_t OFF_U   = OFF_AST;
  constexpr size_t OFF_NRM = OFF_AST + 2 * SZ_STR;
  constexpr size_t OFF_OL  = OFF_NRM;
  constexpr size_t OFF_FE  = OFF_NRM + SZ_MAT;
  constexpr size_t OFF_SQ  = OFF_FE + SZ_MAT;
  constexpr size_t OFF_ST1 = OFF_SQ + (size_t)BQ * NP * 4;
  constexpr size_t OFF_ST2 = OFF_ST1 + (size_t)BQ * CHN * 2 * 4;
  constexpr size_t OFF_NI  = OFF_ST2 + (size_t)BQ * CHN * 2 * 4;

  float* h   = (float*)(ws + OFF_H);
  float* fe  = (float*)(ws + OFF_FE);
  float* nrm = (float*)(ws + OFF_NRM);
  float* sq  = (float*)(ws + OFF_SQ);
  float* st1 = (float*)(ws + OFF_ST1);
  float* st2 = (float*)(ws + OFF_ST2);
  int*   ni  = (int*)(ws + OFF_NI);
  ushort* ast = (ushort*)(ws + OFF_AST);
  ushort* bst = (ushort*)(ws + OFF_BST);
  float* pd  = (float*)(ws + OFF_PD);
  int*   pi  = (int*)(ws + OFF_PI);
  float* aA  = (float*)(ws + OFF_A);
  float* uU  = (float*)(ws + OFF_U);
  float* ol  = (float*)(ws + OFF_OL);

  dim3 g4(NT / 4, MCH, BQ);

  k1_conv1<<<dim3(NP / 64, BQ), 256, 0, stream>>>(x, f1w, f1b, h);
  k2_stats<<<dim3(BQ * CHN), 256, 0, stream>>>(h, st1);
  k3_norm<<<dim3(NP / 32, BQ), 256, 0, stream>>>(h, st1, fe, nrm, sq);
  k3b_prep<<<dim3(NT, BQ), 256, 0, stream>>>(nrm, ast, bst);
  // ---- diagnostic probes (outputs into pd/pi scratch, fully overwritten by real k4) ----
  k4_vb<<<g4, 256, 0, stream>>>(ast, bst, sq, pd, pi);
  k4_vc<<<g4, 256, 0, stream>>>(ast, bst, sq, pd);
  k4_vd<<<g4, 256, 0, stream>>>(ast, pd, pi);
  k4_ve<<<g4, 256, 0, stream>>>(ast, bst, sq, pd, pi);
  // ---- real k4 (unchanged round-5 baseline) ----
  k4_mfma<<<g4, 256, 0, stream>>>(ast, bst, sq, pd, pi);
  k4b_merge<<<dim3(BQ * NP / 64), 64, 0, stream>>>(pd, pi, ni);
  k5_au<<<dim3(NP / 32, BQ), 256, 0, stream>>>(fe, gw, gb, aA, uU);
  k6_edge<<<dim3(NP / 32, BQ), 256, 0, stream>>>(aA, uU, ni, f2w, f2b, ol);
  k2_stats<<<dim3(BQ * CHN), 256, 0, stream>>>(ol, st2);
  k8_final<<<dim3(BQ * CHN * NP / 256), 256, 0, stream>>>(ol, st2, x, out);
}

// Round 9
// 1046.464 us; speedup vs baseline: 3.1117x; 3.1117x over previous
//
#include <hip/hip_runtime.h>
#include <float.h>

#define BQ 8
#define CHN 96
#define NP 3136
#define KNN 9
#define C2 192
#define NT 196        // 16-wide tiles along n/m
#define MCH 4         // m-chunks
#define TPC (NT/MCH)  // 49 tiles per chunk
#define NFRAG 9       // 3-way split: h0,h1,h2,m0,m1,m2,l0,l1,l2
#define NLIST 16      // partial top-9 lists per query (4 m-chunks x 4 lane-groups)

typedef __attribute__((ext_vector_type(8))) short bf16x8;
typedef __attribute__((ext_vector_type(4))) float f32x4;

__device__ inline ushort f2bf(float x) {            // round-to-nearest-even
  unsigned u = __float_as_uint(x);
  return (ushort)((u + 0x7FFFu + ((u >> 16) & 1u)) >> 16);
}
__device__ inline float bf2f(ushort h) { return __uint_as_float((unsigned)h << 16); }

// ONLY verified widths for global_load_lds are 4 and 16 bytes (learn_hip m03/m97).
// Width 12 (rounds 7-8) corrupted LDS (absmax ~3.5) — do not use.
__device__ inline void gl2lds16(const void* g, void* l) {
  __builtin_amdgcn_global_load_lds(
      (const __attribute__((address_space(1))) unsigned int*)g,
      (__attribute__((address_space(3))) unsigned int*)l, 16, 0, 0);
}

// round-5-PROVEN stage: 9 segs of 1KB; wave w does segs {w, w+4}, wave0 also 8
#define STAGE_A(astb_, tg, s) do { \
    const ushort* _src = (astb_) + (size_t)(tg) * (NFRAG * 512); \
    ushort* _dst = lds_a + (s) * (NFRAG * 512); \
    gl2lds16(_src + wave * 512 + lane * 8, _dst + wave * 512); \
    gl2lds16(_src + (wave + 4) * 512 + lane * 8, _dst + (wave + 4) * 512); \
    if (wave == 0) gl2lds16(_src + 8 * 512 + lane * 8, _dst + 8 * 512); \
  } while (0)

#define INSERT9(d, m) do { \
    if ((d) < tv[KNN - 1]) { \
      tv[8] = (d); ti[8] = (m); \
      _Pragma("unroll") \
      for (int j = 8; j > 0; --j) { \
        bool swp = tv[j] < tv[j - 1]; \
        float fa = swp ? tv[j] : tv[j - 1]; \
        float fb = swp ? tv[j - 1] : tv[j]; \
        int ia = swp ? ti[j] : ti[j - 1]; \
        int ib = swp ? ti[j - 1] : ti[j]; \
        tv[j - 1] = fa; tv[j] = fb; ti[j - 1] = ia; ti[j] = ib; \
      } \
    } \
  } while (0)

// ---------- K1: h[b][o][n] = sum_c fc1_w[o][c] * x[b][c][n] + fc1_b[o]
__global__ __launch_bounds__(256) void k1_conv1(const float* __restrict__ x,
    const float* __restrict__ w, const float* __restrict__ bias, float* __restrict__ h) {
  __shared__ float sw[CHN * CHN];
  __shared__ float sx[CHN][64];
  int b = blockIdx.y;
  int n0 = blockIdx.x * 64;
  int tid = threadIdx.x;
  for (int i = tid; i < CHN * CHN; i += 256) sw[i] = w[i];
  const float* xb = x + (size_t)b * CHN * NP + n0;
  for (int i = tid; i < CHN * 64; i += 256) {
    int c = i >> 6, nn = i & 63;
    sx[c][nn] = xb[(size_t)c * NP + nn];
  }
  __syncthreads();
  int nn = tid & 63;
  int o0 = (tid >> 6) * 24;
  float acc[24];
#pragma unroll
  for (int j = 0; j < 24; ++j) acc[j] = 0.f;
  for (int c = 0; c < CHN; ++c) {
    float xv = sx[c][nn];
#pragma unroll
    for (int j = 0; j < 24; ++j) acc[j] = fmaf(sw[(o0 + j) * CHN + c], xv, acc[j]);
  }
  float* hb = h + (size_t)b * CHN * NP + n0;
#pragma unroll
  for (int j = 0; j < 24; ++j) hb[(size_t)(o0 + j) * NP + nn] = acc[j] + bias[o0 + j];
}

// ---------- K2/K7: per-(b,channel) mean + rstd
__global__ __launch_bounds__(256) void k2_stats(const float* __restrict__ src,
                                                float* __restrict__ stat) {
  int bo = blockIdx.x;
  const float* p = src + (size_t)bo * NP;
  float s = 0.f, ss = 0.f;
  for (int i = threadIdx.x; i < NP; i += 256) { float v = p[i]; s += v; ss = fmaf(v, v, ss); }
#pragma unroll
  for (int off = 32; off; off >>= 1) { s += __shfl_down(s, off); ss += __shfl_down(ss, off); }
  __shared__ float as[4], ass[4];
  int wv = threadIdx.x >> 6;
  if ((threadIdx.x & 63) == 0) { as[wv] = s; ass[wv] = ss; }
  __syncthreads();
  if (threadIdx.x == 0) {
    float S = as[0] + as[1] + as[2] + as[3];
    float SS = ass[0] + ass[1] + ass[2] + ass[3];
    float mean = S * (1.f / NP);
    float var = SS * (1.f / NP) - mean * mean;
    if (var < 0.f) var = 0.f;
    stat[bo * 2] = mean;
    stat[bo * 2 + 1] = 1.f / sqrtf(var + 1e-5f);
  }
}

// ---------- K3: normalize h -> feats[b][n][c]; nrm = feats/max(||f||,eps); sq = sum(nrm^2)
__global__ __launch_bounds__(256) void k3_norm(const float* __restrict__ h,
    const float* __restrict__ stat, float* __restrict__ feats, float* __restrict__ nrm,
    float* __restrict__ sq) {
  __shared__ float tile[CHN][33];
  __shared__ float part[8][32];
  __shared__ float sinv[32];
  int b = blockIdx.y, n0 = blockIdx.x * 32;
  int tid = threadIdx.x;
  for (int i = tid; i < CHN * 32; i += 256) {
    int c = i >> 5, nn = i & 31;
    float m = stat[(b * CHN + c) * 2];
    float r = stat[(b * CHN + c) * 2 + 1];
    tile[c][nn] = (h[((size_t)(b * CHN + c)) * NP + n0 + nn] - m) * r;
  }
  __syncthreads();
  int nn = tid & 31, sub = tid >> 5;
  float ss = 0.f;
#pragma unroll
  for (int j = 0; j < 12; ++j) { float f = tile[sub * 12 + j][nn]; ss = fmaf(f, f, ss); }
  part[sub][nn] = ss;
  __syncthreads();
  if (tid < 32) {
    float S = 0.f;
#pragma unroll
    for (int w = 0; w < 8; ++w) S += part[w][tid];
    float norm = sqrtf(S);
    sinv[tid] = 1.f / fmaxf(norm, 1e-12f);
  }
  __syncthreads();
  float inv = sinv[nn];
  float ss2 = 0.f;
#pragma unroll
  for (int j = 0; j < 12; ++j) { float f = tile[sub * 12 + j][nn] * inv; ss2 = fmaf(f, f, ss2); }
  part[sub][nn] = ss2;
  __syncthreads();
  if (tid < 32) {
    float S = 0.f;
#pragma unroll
    for (int w = 0; w < 8; ++w) S += part[w][tid];
    sq[(size_t)b * NP + n0 + tid] = S;
  }
  for (int i = tid; i < 32 * CHN; i += 256) {
    int nn2 = i / CHN, c = i - nn2 * CHN;
    float f = tile[c][nn2];
    size_t o = ((size_t)b * NP + n0 + nn2) * CHN + c;
    feats[o] = f;
    nrm[o] = f * sinv[nn2];
  }
}

// ---------- K3b: build MFMA operand streams, 3-way bf16 split
__global__ __launch_bounds__(256) void k3b_prep(const float* __restrict__ nrm,
    ushort* __restrict__ ast, ushort* __restrict__ bst) {
  int b = blockIdx.y, t = blockIdx.x;
  int tid = threadIdx.x;
  const float* nb = nrm + (size_t)b * NP * CHN;
  ushort* ao = ast + (((size_t)b * NT + t) * NFRAG) * 512;
  for (int e = tid; e < NFRAG * 512; e += 256) {
    int f = e >> 9, l = (e >> 3) & 63, j = e & 7;
    int part = f / 3, sl = f - part * 3;
    int c = sl * 32 + (l >> 4) * 8 + j;
    int m = t * 16 + (l & 15);
    float xv = nb[(size_t)m * CHN + c];
    ushort hh = f2bf(xv);
    float rm = xv - bf2f(hh);          // exact
    ushort md = f2bf(rm);
    ushort v = (part == 0) ? hh : (part == 1) ? md : f2bf(rm - bf2f(md));
    ao[e] = v;
  }
  ushort* bo = bst + (((size_t)b * NT + t) * NFRAG) * 512;
  for (int e = tid; e < NFRAG * 512; e += 256) {
    int f = e >> 9, l = (e >> 3) & 63, j = e & 7;
    int part = f / 3, sl = f - part * 3;
    int c = sl * 32 + (l >> 4) * 8 + j;
    int n = t * 16 + (l & 15);
    float y = -2.f * nb[(size_t)n * CHN + c];
    ushort hh = f2bf(y);
    float rm = y - bf2f(hh);
    ushort md = f2bf(rm);
    ushort v = (part == 0) ? hh : (part == 1) ? md : f2bf(rm - bf2f(md));
    bo[e] = v;
  }
}

// ---------- K4 v5: round-5 structure verbatim (16B staging + one __syncthreads/iter,
// both PROVEN) + register fixes only:
//  (1) B fragments PINNED via opaque asm (kills per-iter remat — round-5's
//      692us pathology at VGPR_Count=52)
//  (2) A frags read per-K-slice (12 live VGPRs, not 36); 4 acc chains
__global__ __launch_bounds__(256, 1) void k4_mfma(
    const ushort* __restrict__ ast, const ushort* __restrict__ bst,
    const float* __restrict__ sq, float* __restrict__ pd, int* __restrict__ pi) {
  int b = blockIdx.z, chunk = blockIdx.y, ng = blockIdx.x;
  int wave = threadIdx.x >> 6, lane = threadIdx.x & 63;
  int tn = ng * 4 + wave;
  const bf16x8* bp = (const bf16x8*)(bst + (((size_t)b * NT + tn) * NFRAG) * 512);
  bf16x8 bh0 = bp[0 * 64 + lane], bh1 = bp[1 * 64 + lane], bh2 = bp[2 * 64 + lane];
  bf16x8 bm0 = bp[3 * 64 + lane], bm1 = bp[4 * 64 + lane], bm2 = bp[5 * 64 + lane];
  bf16x8 bl0 = bp[6 * 64 + lane], bl1 = bp[7 * 64 + lane], bl2 = bp[8 * 64 + lane];
  // pin all 9 B fragments (36 VGPRs) — compiler cannot rematerialize past this
  asm volatile("" : "+v"(bh0), "+v"(bh1), "+v"(bh2),
                    "+v"(bm0), "+v"(bm1), "+v"(bm2),
                    "+v"(bl0), "+v"(bl1), "+v"(bl2));
  const float* sqb = sq + (size_t)b * NP;
  __shared__ ushort lds_a[2 * NFRAG * 512];   // 18,432 B double-buffered A tile
  const ushort* astb = ast + ((size_t)b * NT) * (NFRAG * 512);
  int t0 = chunk * TPC;

  STAGE_A(astb, t0, 0);
  __syncthreads();

  float tv[KNN]; int ti[KNN];
#pragma unroll
  for (int i = 0; i < KNN; ++i) { tv[i] = FLT_MAX; ti[i] = 0x7fffffff; }

  for (int tl = 0; tl < TPC; ++tl) {
    int cur = tl & 1;
    if (tl + 1 < TPC) STAGE_A(astb, t0 + tl + 1, cur ^ 1);   // drained by loop-end barrier

    int mbase = (t0 + tl) * 16 + ((lane >> 4) << 2);
    float4 sqv = *(const float4*)(sqb + mbase);
    const bf16x8* ap = (const bf16x8*)(lds_a + (size_t)cur * (NFRAG * 512));
    f32x4 acc0 = {0.f, 0.f, 0.f, 0.f}, acc1 = {0.f, 0.f, 0.f, 0.f};
    f32x4 acc2 = {0.f, 0.f, 0.f, 0.f}, acc3 = {0.f, 0.f, 0.f, 0.f};
    // slice 0
    bf16x8 a_h = ap[0 * 64 + lane], a_m = ap[3 * 64 + lane], a_l = ap[6 * 64 + lane];
    acc0 = __builtin_amdgcn_mfma_f32_16x16x32_bf16(a_h, bh0, acc0, 0, 0, 0);
    acc1 = __builtin_amdgcn_mfma_f32_16x16x32_bf16(a_m, bh0, acc1, 0, 0, 0);
    acc2 = __builtin_amdgcn_mfma_f32_16x16x32_bf16(a_l, bh0, acc2, 0, 0, 0);
    acc3 = __builtin_amdgcn_mfma_f32_16x16x32_bf16(a_h, bm0, acc3, 0, 0, 0);
    acc2 = __builtin_amdgcn_mfma_f32_16x16x32_bf16(a_h, bl0, acc2, 0, 0, 0);
    acc3 = __builtin_amdgcn_mfma_f32_16x16x32_bf16(a_m, bm0, acc3, 0, 0, 0);
    // slice 1
    a_h = ap[1 * 64 + lane]; a_m = ap[4 * 64 + lane]; a_l = ap[7 * 64 + lane];
    acc0 = __builtin_amdgcn_mfma_f32_16x16x32_bf16(a_h, bh1, acc0, 0, 0, 0);
    acc1 = __builtin_amdgcn_mfma_f32_16x16x32_bf16(a_m, bh1, acc1, 0, 0, 0);
    acc2 = __builtin_amdgcn_mfma_f32_16x16x32_bf16(a_l, bh1, acc2, 0, 0, 0);
    acc3 = __builtin_amdgcn_mfma_f32_16x16x32_bf16(a_h, bm1, acc3, 0, 0, 0);
    acc2 = __builtin_amdgcn_mfma_f32_16x16x32_bf16(a_h, bl1, acc2, 0, 0, 0);
    acc3 = __builtin_amdgcn_mfma_f32_16x16x32_bf16(a_m, bm1, acc3, 0, 0, 0);
    // slice 2
    a_h = ap[2 * 64 + lane]; a_m = ap[5 * 64 + lane]; a_l = ap[8 * 64 + lane];
    acc0 = __builtin_amdgcn_mfma_f32_16x16x32_bf16(a_h, bh2, acc0, 0, 0, 0);
    acc1 = __builtin_amdgcn_mfma_f32_16x16x32_bf16(a_m, bh2, acc1, 0, 0, 0);
    acc2 = __builtin_amdgcn_mfma_f32_16x16x32_bf16(a_l, bh2, acc2, 0, 0, 0);
    acc3 = __builtin_amdgcn_mfma_f32_16x16x32_bf16(a_h, bm2, acc3, 0, 0, 0);
    acc2 = __builtin_amdgcn_mfma_f32_16x16x32_bf16(a_h, bl2, acc2, 0, 0, 0);
    acc3 = __builtin_amdgcn_mfma_f32_16x16x32_bf16(a_m, bm2, acc3, 0, 0, 0);
#pragma unroll
    for (int r = 0; r < 4; ++r) {   // small terms first, then hh, then exact sq_m
      float d = (((acc1[r] + acc3[r]) + acc2[r]) + acc0[r]) + sqv[r];
      INSERT9(d, mbase + r);
    }
    __syncthreads();   // full fence: drains staging (vmcnt) and orders LDS reads
  }
  int g = lane >> 4;
  int n = tn * 16 + (lane & 15);
  size_t base = (((size_t)b * NLIST + (chunk * 4 + g)) * NP + n) * (size_t)KNN;
#pragma unroll
  for (int i = 0; i < KNN; ++i) { pd[base + i] = tv[i]; pi[base + i] = ti[i]; }
}

// ---------- K4b: merge 16 sorted top-9 lists per query
__global__ __launch_bounds__(64) void k4b_merge(const float* __restrict__ pd,
    const int* __restrict__ pi, int* __restrict__ nidx) {
  __shared__ float  sd[64][NLIST * KNN + 1];
  __shared__ ushort si[64][NLIST * KNN + 1];
  int tid = threadIdx.x;
  int q = blockIdx.x * 64 + tid;
  int b = q / NP, n = q - b * NP;
  for (int ch = 0; ch < NLIST; ++ch) {
    size_t base = (((size_t)b * NLIST + ch) * NP + n) * (size_t)KNN;
#pragma unroll
    for (int k = 0; k < KNN; ++k) {
      sd[tid][ch * KNN + k] = pd[base + k];
      si[tid][ch * KNN + k] = (ushort)pi[base + k];
    }
  }
  float dl = -FLT_MAX; int il = -1;
  int* op = nidx + (size_t)q * KNN;
  for (int k = 0; k < KNN; ++k) {
    float bd = FLT_MAX; int bi = 0x7fffffff;
    for (int j = 0; j < NLIST * KNN; ++j) {
      float d = sd[tid][j]; int i = (int)si[tid][j];
      bool gt = (d > dl) || ((d == dl) && (i > il));
      bool lt = (d < bd) || ((d == bd) && (i < bi));
      if (gt && lt) { bd = d; bi = i; }
    }
    op[k] = bi; dl = bd; il = bi;
  }
}

// ---------- K5: a = (W1-W2)·f + gb ; u = W2·f
__global__ __launch_bounds__(256) void k5_au(const float* __restrict__ feats,
    const float* __restrict__ gw, const float* __restrict__ gb,
    float* __restrict__ a, float* __restrict__ u) {
  __shared__ float sf[32][97];
  __shared__ float swc[64 * C2];
  int b = blockIdx.y, n0 = blockIdx.x * 32;
  int tid = threadIdx.x;
  for (int i = tid; i < 32 * CHN; i += 256) {
    int nn = i / CHN, c = i - nn * CHN;
    sf[nn][c] = feats[((size_t)b * NP + n0 + nn) * CHN + c];
  }
  int nn = tid & 31, sub = tid >> 5;
  for (int oc = 0; oc < 3; ++oc) {
    __syncthreads();
    for (int i = tid; i < 64 * C2; i += 256) swc[i] = gw[(size_t)(oc * 64) * C2 + i];
    __syncthreads();
    float accA[8], accU[8];
#pragma unroll
    for (int j = 0; j < 8; ++j) { accA[j] = 0.f; accU[j] = 0.f; }
    for (int c = 0; c < CHN; ++c) {
      float f = sf[nn][c];
#pragma unroll
      for (int j = 0; j < 8; ++j) {
        float w1 = swc[(sub * 8 + j) * C2 + c];
        float wv2 = swc[(sub * 8 + j) * C2 + 96 + c];
        accA[j] = fmaf(w1 - wv2, f, accA[j]);
        accU[j] = fmaf(wv2, f, accU[j]);
      }
    }
    size_t row = ((size_t)b * NP + n0 + nn) * C2;
#pragma unroll
    for (int j = 0; j < 8; ++j) {
      int o = oc * 64 + sub * 8 + j;
      a[row + o] = accA[j] + gb[o];
      u[row + o] = accU[j];
    }
  }
}

// ---------- K6: agg = relu(a + max_k u[idx_k]); ol = fc2_w·agg + fc2_b
__global__ __launch_bounds__(256) void k6_edge(const float* __restrict__ a,
    const float* __restrict__ u, const int* __restrict__ nidx,
    const float* __restrict__ w2, const float* __restrict__ b2, float* __restrict__ ol) {
  __shared__ float sagg[32][193];
  int b = blockIdx.y, n0 = blockIdx.x * 32;
  int tid = threadIdx.x;
  int wv = tid >> 6, ln = tid & 63;
  for (int p = 0; p < 8; ++p) {
    int nn = wv * 8 + p;
    size_t row = (size_t)b * NP + n0 + nn;
    const int* ip = nidx + row * KNN;
    int idx[KNN];
#pragma unroll
    for (int k = 0; k < KNN; ++k) idx[k] = ip[k];
#pragma unroll
    for (int oo = 0; oo < 3; ++oo) {
      int o = oo * 64 + ln;
      float umax = -FLT_MAX;
#pragma unroll
      for (int k = 0; k < KNN; ++k)
        umax = fmaxf(umax, u[((size_t)b * NP + idx[k]) * C2 + o]);
      float av = a[row * C2 + o];
      sagg[nn][o] = fmaxf(av + umax, 0.f);
    }
  }
  __syncthreads();
  int nn = tid & 31, sub = tid >> 5;
  for (int j = 0; j < 12; ++j) {
    int o2 = sub + 8 * j;
    float acc = b2[o2];
    for (int o = 0; o < C2; ++o) acc = fmaf(w2[o2 * C2 + o], sagg[nn][o], acc);
    ol[((size_t)b * CHN + o2) * NP + n0 + nn] = acc;
  }
}

// ---------- K8: out = (ol - mean)*rstd + shortcut
__global__ __launch_bounds__(256) void k8_final(const float* __restrict__ ol,
    const float* __restrict__ stat, const float* __restrict__ x, float* __restrict__ out) {
  int i = blockIdx.x * 256 + threadIdx.x;
  int bo = i / NP;
  float m = stat[bo * 2], r = stat[bo * 2 + 1];
  out[i] = fmaf(ol[i] - m, r, x[i]);
}

extern "C" void kernel_launch(void* const* d_in, const int* in_sizes, int n_in,
                              void* d_out, int out_size, void* d_ws, size_t ws_size,
                              hipStream_t stream) {
  const float* x   = (const float*)d_in[0];
  const float* f1w = (const float*)d_in[1];
  const float* f1b = (const float*)d_in[2];
  const float* gw  = (const float*)d_in[3];
  const float* gb  = (const float*)d_in[4];
  const float* f2w = (const float*)d_in[5];
  const float* f2b = (const float*)d_in[6];
  float* out = (float*)d_out;
  char* ws = (char*)d_ws;

  constexpr size_t SZ_MAT = (size_t)BQ * CHN * NP * 4;           // 9,633,792
  constexpr size_t SZ_STR = (size_t)BQ * NT * NFRAG * 512 * 2;   // 14,450,688
  constexpr size_t SZ_PL  = (size_t)BQ * NLIST * NP * KNN * 4;   // 14,450,688
  constexpr size_t OFF_H   = 0;
  constexpr size_t OFF_PD  = 0;
  constexpr size_t OFF_PI  = OFF_PD + SZ_PL;
  constexpr size_t OFF_A   = 0;
  constexpr size_t OFF_AST = 2 * SZ_PL;
  constexpr size_t OFF_BST = OFF_AST + SZ_STR;
  constexpr size_t OFF_U   = OFF_AST;
  constexpr size_t OFF_NRM = OFF_AST + 2 * SZ_STR;
  constexpr size_t OFF_OL  = OFF_NRM;
  constexpr size_t OFF_FE  = OFF_NRM + SZ_MAT;
  constexpr size_t OFF_SQ  = OFF_FE + SZ_MAT;
  constexpr size_t OFF_ST1 = OFF_SQ + (size_t)BQ * NP * 4;
  constexpr size_t OFF_ST2 = OFF_ST1 + (size_t)BQ * CHN * 2 * 4;
  constexpr size_t OFF_NI  = OFF_ST2 + (size_t)BQ * CHN * 2 * 4;

  float* h   = (float*)(ws + OFF_H);
  float* fe  = (float*)(ws + OFF_FE);
  float* nrm = (float*)(ws + OFF_NRM);
  float* sq  = (float*)(ws + OFF_SQ);
  float* st1 = (float*)(ws + OFF_ST1);
  float* st2 = (float*)(ws + OFF_ST2);
  int*   ni  = (int*)(ws + OFF_NI);
  ushort* ast = (ushort*)(ws + OFF_AST);
  ushort* bst = (ushort*)(ws + OFF_BST);
  float* pd  = (float*)(ws + OFF_PD);
  int*   pi  = (int*)(ws + OFF_PI);
  float* aA  = (float*)(ws + OFF_A);
  float* uU  = (float*)(ws + OFF_U);
  float* ol  = (float*)(ws + OFF_OL);

  k1_conv1<<<dim3(NP / 64, BQ), 256, 0, stream>>>(x, f1w, f1b, h);
  k2_stats<<<dim3(BQ * CHN), 256, 0, stream>>>(h, st1);
  k3_norm<<<dim3(NP / 32, BQ), 256, 0, stream>>>(h, st1, fe, nrm, sq);
  k3b_prep<<<dim3(NT, BQ), 256, 0, stream>>>(nrm, ast, bst);
  k4_mfma<<<dim3(NT / 4, MCH, BQ), 256, 0, stream>>>(ast, bst, sq, pd, pi);
  k4b_merge<<<dim3(BQ * NP / 64), 64, 0, stream>>>(pd, pi, ni);
  k5_au<<<dim3(NP / 32, BQ), 256, 0, stream>>>(fe, gw, gb, aA, uU);
  k6_edge<<<dim3(NP / 32, BQ), 256, 0, stream>>>(aA, uU, ni, f2w, f2b, ol);
  k2_stats<<<dim3(BQ * CHN), 256, 0, stream>>>(ol, st2);
  k8_final<<<dim3(BQ * CHN * NP / 256), 256, 0, stream>>>(ol, st2, x, out);
}

// Round 10
// 1040.298 us; speedup vs baseline: 3.1301x; 1.0059x over previous
//
#include <hip/hip_runtime.h>
#include <float.h>

#define BQ 8
#define CHN 96
#define NP 3136
#define KNN 9
#define C2 192
#define NT 196        // 16-wide tiles along n/m
#define MCH 4         // m-chunks
#define TPC (NT/MCH)  // 49 tiles per chunk
#define NFRAG 9       // 3-way split: h0,h1,h2,m0,m1,m2,l0,l1,l2
#define NLIST 16      // partial top-9 lists per query (4 m-chunks x 4 lane-groups)

typedef __attribute__((ext_vector_type(8))) short bf16x8;
typedef __attribute__((ext_vector_type(4))) float f32x4;

__device__ inline ushort f2bf(float x) {            // round-to-nearest-even
  unsigned u = __float_as_uint(x);
  return (ushort)((u + 0x7FFFu + ((u >> 16) & 1u)) >> 16);
}
__device__ inline float bf2f(ushort h) { return __uint_as_float((unsigned)h << 16); }

#define INSERT9(d, m) do { \
    if ((d) < tv[KNN - 1]) { \
      tv[8] = (d); ti[8] = (m); \
      _Pragma("unroll") \
      for (int j = 8; j > 0; --j) { \
        bool swp = tv[j] < tv[j - 1]; \
        float fa = swp ? tv[j] : tv[j - 1]; \
        float fb = swp ? tv[j - 1] : tv[j]; \
        int ia = swp ? ti[j] : ti[j - 1]; \
        int ib = swp ? ti[j - 1] : ti[j]; \
        tv[j - 1] = fa; tv[j] = fb; ti[j - 1] = ia; ti[j] = ib; \
      } \
    } \
  } while (0)

// ---------- K1: h[b][o][n] = sum_c fc1_w[o][c] * x[b][c][n] + fc1_b[o]
__global__ __launch_bounds__(256) void k1_conv1(const float* __restrict__ x,
    const float* __restrict__ w, const float* __restrict__ bias, float* __restrict__ h) {
  __shared__ float sw[CHN * CHN];
  __shared__ float sx[CHN][64];
  int b = blockIdx.y;
  int n0 = blockIdx.x * 64;
  int tid = threadIdx.x;
  for (int i = tid; i < CHN * CHN; i += 256) sw[i] = w[i];
  const float* xb = x + (size_t)b * CHN * NP + n0;
  for (int i = tid; i < CHN * 64; i += 256) {
    int c = i >> 6, nn = i & 63;
    sx[c][nn] = xb[(size_t)c * NP + nn];
  }
  __syncthreads();
  int nn = tid & 63;
  int o0 = (tid >> 6) * 24;
  float acc[24];
#pragma unroll
  for (int j = 0; j < 24; ++j) acc[j] = 0.f;
  for (int c = 0; c < CHN; ++c) {
    float xv = sx[c][nn];
#pragma unroll
    for (int j = 0; j < 24; ++j) acc[j] = fmaf(sw[(o0 + j) * CHN + c], xv, acc[j]);
  }
  float* hb = h + (size_t)b * CHN * NP + n0;
#pragma unroll
  for (int j = 0; j < 24; ++j) hb[(size_t)(o0 + j) * NP + nn] = acc[j] + bias[o0 + j];
}

// ---------- K2/K7: per-(b,channel) mean + rstd
__global__ __launch_bounds__(256) void k2_stats(const float* __restrict__ src,
                                                float* __restrict__ stat) {
  int bo = blockIdx.x;
  const float* p = src + (size_t)bo * NP;
  float s = 0.f, ss = 0.f;
  for (int i = threadIdx.x; i < NP; i += 256) { float v = p[i]; s += v; ss = fmaf(v, v, ss); }
#pragma unroll
  for (int off = 32; off; off >>= 1) { s += __shfl_down(s, off); ss += __shfl_down(ss, off); }
  __shared__ float as[4], ass[4];
  int wv = threadIdx.x >> 6;
  if ((threadIdx.x & 63) == 0) { as[wv] = s; ass[wv] = ss; }
  __syncthreads();
  if (threadIdx.x == 0) {
    float S = as[0] + as[1] + as[2] + as[3];
    float SS = ass[0] + ass[1] + ass[2] + ass[3];
    float mean = S * (1.f / NP);
    float var = SS * (1.f / NP) - mean * mean;
    if (var < 0.f) var = 0.f;
    stat[bo * 2] = mean;
    stat[bo * 2 + 1] = 1.f / sqrtf(var + 1e-5f);
  }
}

// ---------- K3: normalize h -> feats[b][n][c]; nrm = feats/max(||f||,eps); sq = sum(nrm^2)
__global__ __launch_bounds__(256) void k3_norm(const float* __restrict__ h,
    const float* __restrict__ stat, float* __restrict__ feats, float* __restrict__ nrm,
    float* __restrict__ sq) {
  __shared__ float tile[CHN][33];
  __shared__ float part[8][32];
  __shared__ float sinv[32];
  int b = blockIdx.y, n0 = blockIdx.x * 32;
  int tid = threadIdx.x;
  for (int i = tid; i < CHN * 32; i += 256) {
    int c = i >> 5, nn = i & 31;
    float m = stat[(b * CHN + c) * 2];
    float r = stat[(b * CHN + c) * 2 + 1];
    tile[c][nn] = (h[((size_t)(b * CHN + c)) * NP + n0 + nn] - m) * r;
  }
  __syncthreads();
  int nn = tid & 31, sub = tid >> 5;
  float ss = 0.f;
#pragma unroll
  for (int j = 0; j < 12; ++j) { float f = tile[sub * 12 + j][nn]; ss = fmaf(f, f, ss); }
  part[sub][nn] = ss;
  __syncthreads();
  if (tid < 32) {
    float S = 0.f;
#pragma unroll
    for (int w = 0; w < 8; ++w) S += part[w][tid];
    float norm = sqrtf(S);
    sinv[tid] = 1.f / fmaxf(norm, 1e-12f);
  }
  __syncthreads();
  float inv = sinv[nn];
  float ss2 = 0.f;
#pragma unroll
  for (int j = 0; j < 12; ++j) { float f = tile[sub * 12 + j][nn] * inv; ss2 = fmaf(f, f, ss2); }
  part[sub][nn] = ss2;
  __syncthreads();
  if (tid < 32) {
    float S = 0.f;
#pragma unroll
    for (int w = 0; w < 8; ++w) S += part[w][tid];
    sq[(size_t)b * NP + n0 + tid] = S;
  }
  for (int i = tid; i < 32 * CHN; i += 256) {
    int nn2 = i / CHN, c = i - nn2 * CHN;
    float f = tile[c][nn2];
    size_t o = ((size_t)b * NP + n0 + nn2) * CHN + c;
    feats[o] = f;
    nrm[o] = f * sinv[nn2];
  }
}

// ---------- K3b: build MFMA operand streams, 3-way bf16 split
__global__ __launch_bounds__(256) void k3b_prep(const float* __restrict__ nrm,
    ushort* __restrict__ ast, ushort* __restrict__ bst) {
  int b = blockIdx.y, t = blockIdx.x;
  int tid = threadIdx.x;
  const float* nb = nrm + (size_t)b * NP * CHN;
  ushort* ao = ast + (((size_t)b * NT + t) * NFRAG) * 512;
  for (int e = tid; e < NFRAG * 512; e += 256) {
    int f = e >> 9, l = (e >> 3) & 63, j = e & 7;
    int part = f / 3, sl = f - part * 3;
    int c = sl * 32 + (l >> 4) * 8 + j;
    int m = t * 16 + (l & 15);
    float xv = nb[(size_t)m * CHN + c];
    ushort hh = f2bf(xv);
    float rm = xv - bf2f(hh);          // exact
    ushort md = f2bf(rm);
    ushort v = (part == 0) ? hh : (part == 1) ? md : f2bf(rm - bf2f(md));
    ao[e] = v;
  }
  ushort* bo = bst + (((size_t)b * NT + t) * NFRAG) * 512;
  for (int e = tid; e < NFRAG * 512; e += 256) {
    int f = e >> 9, l = (e >> 3) & 63, j = e & 7;
    int part = f / 3, sl = f - part * 3;
    int c = sl * 32 + (l >> 4) * 8 + j;
    int n = t * 16 + (l & 15);
    float y = -2.f * nb[(size_t)n * CHN + c];
    ushort hh = f2bf(y);
    float rm = y - bf2f(hh);
    ushort md = f2bf(rm);
    ushort v = (part == 0) ? hh : (part == 1) ? md : f2bf(rm - bf2f(md));
    bo[e] = v;
  }
}

// ---------- K4 v6 ("VE + prefetch"): NO LDS, NO barriers.
// Round-6 probe arithmetic showed the block-wide stage+__syncthreads skeleton
// itself cost ~600us (VC~600/VD~650 inherit it, barrier-free VE~100 escapes).
// Each wave: B fragments in regs (loaded once); A fragments read straight from
// global (coalesced 16B/lane; L1-shared across the block's 4 waves which walk
// the same m-chunk), software-pipelined one tile ahead in NAMED registers
// (no runtime-indexed arrays -> no scratch). Only sync: per-wave load waits.
__global__ __launch_bounds__(256)
__attribute__((amdgpu_waves_per_eu(1, 4)))
void k4_mfma(
    const ushort* __restrict__ ast, const ushort* __restrict__ bst,
    const float* __restrict__ sq, float* __restrict__ pd, int* __restrict__ pi) {
  int b = blockIdx.z, chunk = blockIdx.y, ng = blockIdx.x;
  int wave = threadIdx.x >> 6, lane = threadIdx.x & 63;
  int tn = ng * 4 + wave;
  const bf16x8* bp = (const bf16x8*)(bst + (((size_t)b * NT + tn) * NFRAG) * 512);
  bf16x8 bh0 = bp[0 * 64 + lane], bh1 = bp[1 * 64 + lane], bh2 = bp[2 * 64 + lane];
  bf16x8 bm0 = bp[3 * 64 + lane], bm1 = bp[4 * 64 + lane], bm2 = bp[5 * 64 + lane];
  bf16x8 bl0 = bp[6 * 64 + lane], bl1 = bp[7 * 64 + lane], bl2 = bp[8 * 64 + lane];
  asm volatile("" : "+v"(bh0), "+v"(bh1), "+v"(bh2),
                    "+v"(bm0), "+v"(bm1), "+v"(bm2),
                    "+v"(bl0), "+v"(bl1), "+v"(bl2));
  const float* sqb = sq + (size_t)b * NP;
  const ushort* astb = ast + ((size_t)b * NT) * (NFRAG * 512);
  int t0 = chunk * TPC;
  const size_t TS = (size_t)NFRAG * 512;

#define LDA(dst, base, f) dst = ((const bf16x8*)(base))[(f) * 64 + lane]

  // current-tile A fragments (tile t0)
  const ushort* cp = astb + (size_t)t0 * TS;
  bf16x8 cA0, cA1, cA2, cA3, cA4, cA5, cA6, cA7, cA8;
  LDA(cA0, cp, 0); LDA(cA1, cp, 1); LDA(cA2, cp, 2);
  LDA(cA3, cp, 3); LDA(cA4, cp, 4); LDA(cA5, cp, 5);
  LDA(cA6, cp, 6); LDA(cA7, cp, 7); LDA(cA8, cp, 8);

  float tv[KNN]; int ti[KNN];
#pragma unroll
  for (int i = 0; i < KNN; ++i) { tv[i] = FLT_MAX; ti[i] = 0x7fffffff; }

  for (int tl = 0; tl < TPC; ++tl) {
    bf16x8 nA0, nA1, nA2, nA3, nA4, nA5, nA6, nA7, nA8;
    bool more = (tl + 1 < TPC);
    if (more) {   // prefetch next tile into named regs; latency hides under MFMAs
      const ushort* np = astb + (size_t)(t0 + tl + 1) * TS;
      LDA(nA0, np, 0); LDA(nA1, np, 1); LDA(nA2, np, 2);
      LDA(nA3, np, 3); LDA(nA4, np, 4); LDA(nA5, np, 5);
      LDA(nA6, np, 6); LDA(nA7, np, 7); LDA(nA8, np, 8);
    }
    int mbase = (t0 + tl) * 16 + ((lane >> 4) << 2);
    float4 sqv = *(const float4*)(sqb + mbase);
    f32x4 acc0 = {0.f, 0.f, 0.f, 0.f}, acc1 = {0.f, 0.f, 0.f, 0.f};
    f32x4 acc2 = {0.f, 0.f, 0.f, 0.f}, acc3 = {0.f, 0.f, 0.f, 0.f};
    // slice 0: a_h=cA0 a_m=cA3 a_l=cA6
    acc0 = __builtin_amdgcn_mfma_f32_16x16x32_bf16(cA0, bh0, acc0, 0, 0, 0);
    acc1 = __builtin_amdgcn_mfma_f32_16x16x32_bf16(cA3, bh0, acc1, 0, 0, 0);
    acc2 = __builtin_amdgcn_mfma_f32_16x16x32_bf16(cA6, bh0, acc2, 0, 0, 0);
    acc3 = __builtin_amdgcn_mfma_f32_16x16x32_bf16(cA0, bm0, acc3, 0, 0, 0);
    acc2 = __builtin_amdgcn_mfma_f32_16x16x32_bf16(cA0, bl0, acc2, 0, 0, 0);
    acc3 = __builtin_amdgcn_mfma_f32_16x16x32_bf16(cA3, bm0, acc3, 0, 0, 0);
    // slice 1: cA1 cA4 cA7
    acc0 = __builtin_amdgcn_mfma_f32_16x16x32_bf16(cA1, bh1, acc0, 0, 0, 0);
    acc1 = __builtin_amdgcn_mfma_f32_16x16x32_bf16(cA4, bh1, acc1, 0, 0, 0);
    acc2 = __builtin_amdgcn_mfma_f32_16x16x32_bf16(cA7, bh1, acc2, 0, 0, 0);
    acc3 = __builtin_amdgcn_mfma_f32_16x16x32_bf16(cA1, bm1, acc3, 0, 0, 0);
    acc2 = __builtin_amdgcn_mfma_f32_16x16x32_bf16(cA1, bl1, acc2, 0, 0, 0);
    acc3 = __builtin_amdgcn_mfma_f32_16x16x32_bf16(cA4, bm1, acc3, 0, 0, 0);
    // slice 2: cA2 cA5 cA8
    acc0 = __builtin_amdgcn_mfma_f32_16x16x32_bf16(cA2, bh2, acc0, 0, 0, 0);
    acc1 = __builtin_amdgcn_mfma_f32_16x16x32_bf16(cA5, bh2, acc1, 0, 0, 0);
    acc2 = __builtin_amdgcn_mfma_f32_16x16x32_bf16(cA8, bh2, acc2, 0, 0, 0);
    acc3 = __builtin_amdgcn_mfma_f32_16x16x32_bf16(cA2, bm2, acc3, 0, 0, 0);
    acc2 = __builtin_amdgcn_mfma_f32_16x16x32_bf16(cA2, bl2, acc2, 0, 0, 0);
    acc3 = __builtin_amdgcn_mfma_f32_16x16x32_bf16(cA5, bm2, acc3, 0, 0, 0);
#pragma unroll
    for (int r = 0; r < 4; ++r) {   // small terms first, then hh, then exact sq_m
      float d = (((acc1[r] + acc3[r]) + acc2[r]) + acc0[r]) + sqv[r];
      INSERT9(d, mbase + r);
    }
    if (more) {
      cA0 = nA0; cA1 = nA1; cA2 = nA2; cA3 = nA3; cA4 = nA4;
      cA5 = nA5; cA6 = nA6; cA7 = nA7; cA8 = nA8;
    }
  }
#undef LDA
  int g = lane >> 4;
  int n = tn * 16 + (lane & 15);
  size_t base = (((size_t)b * NLIST + (chunk * 4 + g)) * NP + n) * (size_t)KNN;
#pragma unroll
  for (int i = 0; i < KNN; ++i) { pd[base + i] = tv[i]; pi[base + i] = ti[i]; }
}

// ---------- K4b: merge 16 sorted top-9 lists per query
__global__ __launch_bounds__(64) void k4b_merge(const float* __restrict__ pd,
    const int* __restrict__ pi, int* __restrict__ nidx) {
  __shared__ float  sd[64][NLIST * KNN + 1];
  __shared__ ushort si[64][NLIST * KNN + 1];
  int tid = threadIdx.x;
  int q = blockIdx.x * 64 + tid;
  int b = q / NP, n = q - b * NP;
  for (int ch = 0; ch < NLIST; ++ch) {
    size_t base = (((size_t)b * NLIST + ch) * NP + n) * (size_t)KNN;
#pragma unroll
    for (int k = 0; k < KNN; ++k) {
      sd[tid][ch * KNN + k] = pd[base + k];
      si[tid][ch * KNN + k] = (ushort)pi[base + k];
    }
  }
  float dl = -FLT_MAX; int il = -1;
  int* op = nidx + (size_t)q * KNN;
  for (int k = 0; k < KNN; ++k) {
    float bd = FLT_MAX; int bi = 0x7fffffff;
    for (int j = 0; j < NLIST * KNN; ++j) {
      float d = sd[tid][j]; int i = (int)si[tid][j];
      bool gt = (d > dl) || ((d == dl) && (i > il));
      bool lt = (d < bd) || ((d == bd) && (i < bi));
      if (gt && lt) { bd = d; bi = i; }
    }
    op[k] = bi; dl = bd; il = bi;
  }
}

// ---------- K5: a = (W1-W2)·f + gb ; u = W2·f
__global__ __launch_bounds__(256) void k5_au(const float* __restrict__ feats,
    const float* __restrict__ gw, const float* __restrict__ gb,
    float* __restrict__ a, float* __restrict__ u) {
  __shared__ float sf[32][97];
  __shared__ float swc[64 * C2];
  int b = blockIdx.y, n0 = blockIdx.x * 32;
  int tid = threadIdx.x;
  for (int i = tid; i < 32 * CHN; i += 256) {
    int nn = i / CHN, c = i - nn * CHN;
    sf[nn][c] = feats[((size_t)b * NP + n0 + nn) * CHN + c];
  }
  int nn = tid & 31, sub = tid >> 5;
  for (int oc = 0; oc < 3; ++oc) {
    __syncthreads();
    for (int i = tid; i < 64 * C2; i += 256) swc[i] = gw[(size_t)(oc * 64) * C2 + i];
    __syncthreads();
    float accA[8], accU[8];
#pragma unroll
    for (int j = 0; j < 8; ++j) { accA[j] = 0.f; accU[j] = 0.f; }
    for (int c = 0; c < CHN; ++c) {
      float f = sf[nn][c];
#pragma unroll
      for (int j = 0; j < 8; ++j) {
        float w1 = swc[(sub * 8 + j) * C2 + c];
        float wv2 = swc[(sub * 8 + j) * C2 + 96 + c];
        accA[j] = fmaf(w1 - wv2, f, accA[j]);
        accU[j] = fmaf(wv2, f, accU[j]);
      }
    }
    size_t row = ((size_t)b * NP + n0 + nn) * C2;
#pragma unroll
    for (int j = 0; j < 8; ++j) {
      int o = oc * 64 + sub * 8 + j;
      a[row + o] = accA[j] + gb[o];
      u[row + o] = accU[j];
    }
  }
}

// ---------- K6: agg = relu(a + max_k u[idx_k]); ol = fc2_w·agg + fc2_b
__global__ __launch_bounds__(256) void k6_edge(const float* __restrict__ a,
    const float* __restrict__ u, const int* __restrict__ nidx,
    const float* __restrict__ w2, const float* __restrict__ b2, float* __restrict__ ol) {
  __shared__ float sagg[32][193];
  int b = blockIdx.y, n0 = blockIdx.x * 32;
  int tid = threadIdx.x;
  int wv = tid >> 6, ln = tid & 63;
  for (int p = 0; p < 8; ++p) {
    int nn = wv * 8 + p;
    size_t row = (size_t)b * NP + n0 + nn;
    const int* ip = nidx + row * KNN;
    int idx[KNN];
#pragma unroll
    for (int k = 0; k < KNN; ++k) idx[k] = ip[k];
#pragma unroll
    for (int oo = 0; oo < 3; ++oo) {
      int o = oo * 64 + ln;
      float umax = -FLT_MAX;
#pragma unroll
      for (int k = 0; k < KNN; ++k)
        umax = fmaxf(umax, u[((size_t)b * NP + idx[k]) * C2 + o]);
      float av = a[row * C2 + o];
      sagg[nn][o] = fmaxf(av + umax, 0.f);
    }
  }
  __syncthreads();
  int nn = tid & 31, sub = tid >> 5;
  for (int j = 0; j < 12; ++j) {
    int o2 = sub + 8 * j;
    float acc = b2[o2];
    for (int o = 0; o < C2; ++o) acc = fmaf(w2[o2 * C2 + o], sagg[nn][o], acc);
    ol[((size_t)b * CHN + o2) * NP + n0 + nn] = acc;
  }
}

// ---------- K8: out = (ol - mean)*rstd + shortcut
__global__ __launch_bounds__(256) void k8_final(const float* __restrict__ ol,
    const float* __restrict__ stat, const float* __restrict__ x, float* __restrict__ out) {
  int i = blockIdx.x * 256 + threadIdx.x;
  int bo = i / NP;
  float m = stat[bo * 2], r = stat[bo * 2 + 1];
  out[i] = fmaf(ol[i] - m, r, x[i]);
}

extern "C" void kernel_launch(void* const* d_in, const int* in_sizes, int n_in,
                              void* d_out, int out_size, void* d_ws, size_t ws_size,
                              hipStream_t stream) {
  const float* x   = (const float*)d_in[0];
  const float* f1w = (const float*)d_in[1];
  const float* f1b = (const float*)d_in[2];
  const float* gw  = (const float*)d_in[3];
  const float* gb  = (const float*)d_in[4];
  const float* f2w = (const float*)d_in[5];
  const float* f2b = (const float*)d_in[6];
  float* out = (float*)d_out;
  char* ws = (char*)d_ws;

  constexpr size_t SZ_MAT = (size_t)BQ * CHN * NP * 4;           // 9,633,792
  constexpr size_t SZ_STR = (size_t)BQ * NT * NFRAG * 512 * 2;   // 14,450,688
  constexpr size_t SZ_PL  = (size_t)BQ * NLIST * NP * KNN * 4;   // 14,450,688
  constexpr size_t OFF_H   = 0;
  constexpr size_t OFF_PD  = 0;
  constexpr size_t OFF_PI  = OFF_PD + SZ_PL;
  constexpr size_t OFF_A   = 0;
  constexpr size_t OFF_AST = 2 * SZ_PL;
  constexpr size_t OFF_BST = OFF_AST + SZ_STR;
  constexpr size_t OFF_U   = OFF_AST;
  constexpr size_t OFF_NRM = OFF_AST + 2 * SZ_STR;
  constexpr size_t OFF_OL  = OFF_NRM;
  constexpr size_t OFF_FE  = OFF_NRM + SZ_MAT;
  constexpr size_t OFF_SQ  = OFF_FE + SZ_MAT;
  constexpr size_t OFF_ST1 = OFF_SQ + (size_t)BQ * NP * 4;
  constexpr size_t OFF_ST2 = OFF_ST1 + (size_t)BQ * CHN * 2 * 4;
  constexpr size_t OFF_NI  = OFF_ST2 + (size_t)BQ * CHN * 2 * 4;

  float* h   = (float*)(ws + OFF_H);
  float* fe  = (float*)(ws + OFF_FE);
  float* nrm = (float*)(ws + OFF_NRM);
  float* sq  = (float*)(ws + OFF_SQ);
  float* st1 = (float*)(ws + OFF_ST1);
  float* st2 = (float*)(ws + OFF_ST2);
  int*   ni  = (int*)(ws + OFF_NI);
  ushort* ast = (ushort*)(ws + OFF_AST);
  ushort* bst = (ushort*)(ws + OFF_BST);
  float* pd  = (float*)(ws + OFF_PD);
  int*   pi  = (int*)(ws + OFF_PI);
  float* aA  = (float*)(ws + OFF_A);
  float* uU  = (float*)(ws + OFF_U);
  float* ol  = (float*)(ws + OFF_OL);

  k1_conv1<<<dim3(NP / 64, BQ), 256, 0, stream>>>(x, f1w, f1b, h);
  k2_stats<<<dim3(BQ * CHN), 256, 0, stream>>>(h, st1);
  k3_norm<<<dim3(NP / 32, BQ), 256, 0, stream>>>(h, st1, fe, nrm, sq);
  k3b_prep<<<dim3(NT, BQ), 256, 0, stream>>>(nrm, ast, bst);
  k4_mfma<<<dim3(NT / 4, MCH, BQ), 256, 0, stream>>>(ast, bst, sq, pd, pi);
  k4b_merge<<<dim3(BQ * NP / 64), 64, 0, stream>>>(pd, pi, ni);
  k5_au<<<dim3(NP / 32, BQ), 256, 0, stream>>>(fe, gw, gb, aA, uU);
  k6_edge<<<dim3(NP / 32, BQ), 256, 0, stream>>>(aA, uU, ni, f2w, f2b, ol);
  k2_stats<<<dim3(BQ * CHN), 256, 0, stream>>>(ol, st2);
  k8_final<<<dim3(BQ * CHN * NP / 256), 256, 0, stream>>>(ol, st2, x, out);
}

// Round 11
// 543.351 us; speedup vs baseline: 5.9929x; 1.9146x over previous
//
#include <hip/hip_runtime.h>
#include <float.h>

#define BQ 8
#define CHN 96
#define NP 3136
#define KNN 9
#define C2 192
#define NT 196        // 16-wide tiles along n/m
#define MCH 4         // m-chunks
#define TPC (NT/MCH)  // 49 tiles per chunk
#define NFRAG 9       // 3-way split: h0,h1,h2,m0,m1,m2,l0,l1,l2
#define NLIST 16      // partial top-9 lists per query (4 m-chunks x 4 lane-groups)

typedef __attribute__((ext_vector_type(8))) short bf16x8;
typedef __attribute__((ext_vector_type(4))) float f32x4;

__device__ inline ushort f2bf(float x) {            // round-to-nearest-even
  unsigned u = __float_as_uint(x);
  return (ushort)((u + 0x7FFFu + ((u >> 16) & 1u)) >> 16);
}
__device__ inline float bf2f(ushort h) { return __uint_as_float((unsigned)h << 16); }

// ---------- K1: h[b][o][n] = sum_c fc1_w[o][c] * x[b][c][n] + fc1_b[o]
__global__ __launch_bounds__(256) void k1_conv1(const float* __restrict__ x,
    const float* __restrict__ w, const float* __restrict__ bias, float* __restrict__ h) {
  __shared__ float sw[CHN * CHN];
  __shared__ float sx[CHN][64];
  int b = blockIdx.y;
  int n0 = blockIdx.x * 64;
  int tid = threadIdx.x;
  for (int i = tid; i < CHN * CHN; i += 256) sw[i] = w[i];
  const float* xb = x + (size_t)b * CHN * NP + n0;
  for (int i = tid; i < CHN * 64; i += 256) {
    int c = i >> 6, nn = i & 63;
    sx[c][nn] = xb[(size_t)c * NP + nn];
  }
  __syncthreads();
  int nn = tid & 63;
  int o0 = (tid >> 6) * 24;
  float acc[24];
#pragma unroll
  for (int j = 0; j < 24; ++j) acc[j] = 0.f;
  for (int c = 0; c < CHN; ++c) {
    float xv = sx[c][nn];
#pragma unroll
    for (int j = 0; j < 24; ++j) acc[j] = fmaf(sw[(o0 + j) * CHN + c], xv, acc[j]);
  }
  float* hb = h + (size_t)b * CHN * NP + n0;
#pragma unroll
  for (int j = 0; j < 24; ++j) hb[(size_t)(o0 + j) * NP + nn] = acc[j] + bias[o0 + j];
}

// ---------- K2/K7: per-(b,channel) mean + rstd
__global__ __launch_bounds__(256) void k2_stats(const float* __restrict__ src,
                                                float* __restrict__ stat) {
  int bo = blockIdx.x;
  const float* p = src + (size_t)bo * NP;
  float s = 0.f, ss = 0.f;
  for (int i = threadIdx.x; i < NP; i += 256) { float v = p[i]; s += v; ss = fmaf(v, v, ss); }
#pragma unroll
  for (int off = 32; off; off >>= 1) { s += __shfl_down(s, off); ss += __shfl_down(ss, off); }
  __shared__ float as[4], ass[4];
  int wv = threadIdx.x >> 6;
  if ((threadIdx.x & 63) == 0) { as[wv] = s; ass[wv] = ss; }
  __syncthreads();
  if (threadIdx.x == 0) {
    float S = as[0] + as[1] + as[2] + as[3];
    float SS = ass[0] + ass[1] + ass[2] + ass[3];
    float mean = S * (1.f / NP);
    float var = SS * (1.f / NP) - mean * mean;
    if (var < 0.f) var = 0.f;
    stat[bo * 2] = mean;
    stat[bo * 2 + 1] = 1.f / sqrtf(var + 1e-5f);
  }
}

// ---------- K3: normalize h -> feats[b][n][c]; nrm = feats/max(||f||,eps); sq = sum(nrm^2)
__global__ __launch_bounds__(256) void k3_norm(const float* __restrict__ h,
    const float* __restrict__ stat, float* __restrict__ feats, float* __restrict__ nrm,
    float* __restrict__ sq) {
  __shared__ float tile[CHN][33];
  __shared__ float part[8][32];
  __shared__ float sinv[32];
  int b = blockIdx.y, n0 = blockIdx.x * 32;
  int tid = threadIdx.x;
  for (int i = tid; i < CHN * 32; i += 256) {
    int c = i >> 5, nn = i & 31;
    float m = stat[(b * CHN + c) * 2];
    float r = stat[(b * CHN + c) * 2 + 1];
    tile[c][nn] = (h[((size_t)(b * CHN + c)) * NP + n0 + nn] - m) * r;
  }
  __syncthreads();
  int nn = tid & 31, sub = tid >> 5;
  float ss = 0.f;
#pragma unroll
  for (int j = 0; j < 12; ++j) { float f = tile[sub * 12 + j][nn]; ss = fmaf(f, f, ss); }
  part[sub][nn] = ss;
  __syncthreads();
  if (tid < 32) {
    float S = 0.f;
#pragma unroll
    for (int w = 0; w < 8; ++w) S += part[w][tid];
    float norm = sqrtf(S);
    sinv[tid] = 1.f / fmaxf(norm, 1e-12f);
  }
  __syncthreads();
  float inv = sinv[nn];
  float ss2 = 0.f;
#pragma unroll
  for (int j = 0; j < 12; ++j) { float f = tile[sub * 12 + j][nn] * inv; ss2 = fmaf(f, f, ss2); }
  part[sub][nn] = ss2;
  __syncthreads();
  if (tid < 32) {
    float S = 0.f;
#pragma unroll
    for (int w = 0; w < 8; ++w) S += part[w][tid];
    sq[(size_t)b * NP + n0 + tid] = S;
  }
  for (int i = tid; i < 32 * CHN; i += 256) {
    int nn2 = i / CHN, c = i - nn2 * CHN;
    float f = tile[c][nn2];
    size_t o = ((size_t)b * NP + n0 + nn2) * CHN + c;
    feats[o] = f;
    nrm[o] = f * sinv[nn2];
  }
}

// ---------- K3b: build MFMA operand streams, 3-way bf16 split
__global__ __launch_bounds__(256) void k3b_prep(const float* __restrict__ nrm,
    ushort* __restrict__ ast, ushort* __restrict__ bst) {
  int b = blockIdx.y, t = blockIdx.x;
  int tid = threadIdx.x;
  const float* nb = nrm + (size_t)b * NP * CHN;
  ushort* ao = ast + (((size_t)b * NT + t) * NFRAG) * 512;
  for (int e = tid; e < NFRAG * 512; e += 256) {
    int f = e >> 9, l = (e >> 3) & 63, j = e & 7;
    int part = f / 3, sl = f - part * 3;
    int c = sl * 32 + (l >> 4) * 8 + j;
    int m = t * 16 + (l & 15);
    float xv = nb[(size_t)m * CHN + c];
    ushort hh = f2bf(xv);
    float rm = xv - bf2f(hh);          // exact
    ushort md = f2bf(rm);
    ushort v = (part == 0) ? hh : (part == 1) ? md : f2bf(rm - bf2f(md));
    ao[e] = v;
  }
  ushort* bo = bst + (((size_t)b * NT + t) * NFRAG) * 512;
  for (int e = tid; e < NFRAG * 512; e += 256) {
    int f = e >> 9, l = (e >> 3) & 63, j = e & 7;
    int part = f / 3, sl = f - part * 3;
    int c = sl * 32 + (l >> 4) * 8 + j;
    int n = t * 16 + (l & 15);
    float y = -2.f * nb[(size_t)n * CHN + c];
    ushort hh = f2bf(y);
    float rm = y - bf2f(hh);
    ushort md = f2bf(rm);
    ushort v = (part == 0) ? hh : (part == 1) ? md : f2bf(rm - bf2f(md));
    bo[e] = v;
  }
}

// ---------- K4 v7: budget-engineered (~90 live VGPRs) — every prior variant
// (rounds 1,5,9,10: 692-975us at VGPR 52-92) was scratch-spilled; structure was
// irrelevant. v7 fits the register file:
//   - B fragments in WAVE-PRIVATE LDS (written once, no barriers ever; only
//     the owning wave reads) -> 8 live B regs instead of 36
//   - A: 9 upfront global loads per tile (compiler sinks vmcnt to first use)
//   - top-9 in 18 NAMED scalars (no arrays -> scratch demotion impossible)
#define CSWAP(vI, iI, vJ, iJ) do { \
    bool _s = (vJ) < (vI); \
    float _fa = _s ? (vJ) : (vI); float _fb = _s ? (vI) : (vJ); \
    int _ia = _s ? (iJ) : (iI); int _ib = _s ? (iI) : (iJ); \
    (vI) = _fa; (vJ) = _fb; (iI) = _ia; (iJ) = _ib; \
  } while (0)

__global__ __launch_bounds__(256) void k4_mfma(
    const ushort* __restrict__ ast, const ushort* __restrict__ bst,
    const float* __restrict__ sq, float* __restrict__ pd, int* __restrict__ pi) {
  int b = blockIdx.z, chunk = blockIdx.y, ng = blockIdx.x;
  int wave = threadIdx.x >> 6, lane = threadIdx.x & 63;
  int tn = ng * 4 + wave;

  // B tile -> wave-private LDS (once). No __syncthreads needed anywhere:
  // each wave reads only its own region; in-wave ds ordering via lgkmcnt.
  __shared__ ushort lds_b[4 * NFRAG * 512];   // 36,864 B
  {
    const bf16x8* bp = (const bf16x8*)(bst + (((size_t)b * NT + tn) * NFRAG) * 512);
    bf16x8* dst = (bf16x8*)(lds_b + wave * (NFRAG * 512));
#pragma unroll
    for (int f = 0; f < NFRAG; ++f) dst[f * 64 + lane] = bp[f * 64 + lane];
  }
  const bf16x8* bl = (const bf16x8*)(lds_b + wave * (NFRAG * 512));

  const float* sqb = sq + (size_t)b * NP;
  const ushort* astb = ast + ((size_t)b * NT) * (NFRAG * 512);
  int t0 = chunk * TPC;
  const size_t TS = (size_t)NFRAG * 512;

  float tv0 = FLT_MAX, tv1 = FLT_MAX, tv2 = FLT_MAX, tv3 = FLT_MAX, tv4 = FLT_MAX;
  float tv5 = FLT_MAX, tv6 = FLT_MAX, tv7 = FLT_MAX, tv8 = FLT_MAX;
  int ti0 = 0x7fffffff, ti1 = 0x7fffffff, ti2 = 0x7fffffff, ti3 = 0x7fffffff;
  int ti4 = 0x7fffffff, ti5 = 0x7fffffff, ti6 = 0x7fffffff, ti7 = 0x7fffffff;
  int ti8 = 0x7fffffff;

  for (int tl = 0; tl < TPC; ++tl) {
    const bf16x8* ap = (const bf16x8*)(astb + (size_t)(t0 + tl) * TS);
    // all 9 A fragments up front — compiler batches loads, sinks waits
    bf16x8 aH0 = ap[0 * 64 + lane], aH1 = ap[1 * 64 + lane], aH2 = ap[2 * 64 + lane];
    bf16x8 aM0 = ap[3 * 64 + lane], aM1 = ap[4 * 64 + lane], aM2 = ap[5 * 64 + lane];
    bf16x8 aL0 = ap[6 * 64 + lane], aL1 = ap[7 * 64 + lane], aL2 = ap[8 * 64 + lane];
    int mbase = (t0 + tl) * 16 + ((lane >> 4) << 2);
    float4 sqv = *(const float4*)(sqb + mbase);
    f32x4 acc0 = {0.f, 0.f, 0.f, 0.f}, acc1 = {0.f, 0.f, 0.f, 0.f};
    f32x4 acc2 = {0.f, 0.f, 0.f, 0.f}, acc3 = {0.f, 0.f, 0.f, 0.f};
#pragma unroll
    for (int s = 0; s < 3; ++s) {
      bf16x8 aH = (s == 0) ? aH0 : (s == 1) ? aH1 : aH2;
      bf16x8 aM = (s == 0) ? aM0 : (s == 1) ? aM1 : aM2;
      bf16x8 aL = (s == 0) ? aL0 : (s == 1) ? aL1 : aL2;
      bf16x8 bH = bl[(0 + s) * 64 + lane];   // just-in-time B reads: 8 live regs
      bf16x8 bM = bl[(3 + s) * 64 + lane];
      bf16x8 bL = bl[(6 + s) * 64 + lane];
      acc0 = __builtin_amdgcn_mfma_f32_16x16x32_bf16(aH, bH, acc0, 0, 0, 0);
      acc1 = __builtin_amdgcn_mfma_f32_16x16x32_bf16(aM, bH, acc1, 0, 0, 0);
      acc2 = __builtin_amdgcn_mfma_f32_16x16x32_bf16(aL, bH, acc2, 0, 0, 0);
      acc3 = __builtin_amdgcn_mfma_f32_16x16x32_bf16(aH, bM, acc3, 0, 0, 0);
      acc2 = __builtin_amdgcn_mfma_f32_16x16x32_bf16(aH, bL, acc2, 0, 0, 0);
      acc3 = __builtin_amdgcn_mfma_f32_16x16x32_bf16(aM, bM, acc3, 0, 0, 0);
    }
#pragma unroll
    for (int r = 0; r < 4; ++r) {   // small terms first, then hh, then exact sq_m
      float d = (((acc1[r] + acc3[r]) + acc2[r]) + acc0[r]) + sqv[r];
      int m = mbase + r;
      if (d < tv8) {                // strict <: equal keys keep earlier index
        tv8 = d; ti8 = m;
        CSWAP(tv7, ti7, tv8, ti8);
        CSWAP(tv6, ti6, tv7, ti7);
        CSWAP(tv5, ti5, tv6, ti6);
        CSWAP(tv4, ti4, tv5, ti5);
        CSWAP(tv3, ti3, tv4, ti4);
        CSWAP(tv2, ti2, tv3, ti3);
        CSWAP(tv1, ti1, tv2, ti2);
        CSWAP(tv0, ti0, tv1, ti1);
      }
    }
  }
  int g = lane >> 4;
  int n = tn * 16 + (lane & 15);
  size_t base = (((size_t)b * NLIST + (chunk * 4 + g)) * NP + n) * (size_t)KNN;
  pd[base + 0] = tv0; pi[base + 0] = ti0;
  pd[base + 1] = tv1; pi[base + 1] = ti1;
  pd[base + 2] = tv2; pi[base + 2] = ti2;
  pd[base + 3] = tv3; pi[base + 3] = ti3;
  pd[base + 4] = tv4; pi[base + 4] = ti4;
  pd[base + 5] = tv5; pi[base + 5] = ti5;
  pd[base + 6] = tv6; pi[base + 6] = ti6;
  pd[base + 7] = tv7; pi[base + 7] = ti7;
  pd[base + 8] = tv8; pi[base + 8] = ti8;
}

// ---------- K4b: merge 16 sorted top-9 lists per query
__global__ __launch_bounds__(64) void k4b_merge(const float* __restrict__ pd,
    const int* __restrict__ pi, int* __restrict__ nidx) {
  __shared__ float  sd[64][NLIST * KNN + 1];
  __shared__ ushort si[64][NLIST * KNN + 1];
  int tid = threadIdx.x;
  int q = blockIdx.x * 64 + tid;
  int b = q / NP, n = q - b * NP;
  for (int ch = 0; ch < NLIST; ++ch) {
    size_t base = (((size_t)b * NLIST + ch) * NP + n) * (size_t)KNN;
#pragma unroll
    for (int k = 0; k < KNN; ++k) {
      sd[tid][ch * KNN + k] = pd[base + k];
      si[tid][ch * KNN + k] = (ushort)pi[base + k];
    }
  }
  float dl = -FLT_MAX; int il = -1;
  int* op = nidx + (size_t)q * KNN;
  for (int k = 0; k < KNN; ++k) {
    float bd = FLT_MAX; int bi = 0x7fffffff;
    for (int j = 0; j < NLIST * KNN; ++j) {
      float d = sd[tid][j]; int i = (int)si[tid][j];
      bool gt = (d > dl) || ((d == dl) && (i > il));
      bool lt = (d < bd) || ((d == bd) && (i < bi));
      if (gt && lt) { bd = d; bi = i; }
    }
    op[k] = bi; dl = bd; il = bi;
  }
}

// ---------- K5: a = (W1-W2)·f + gb ; u = W2·f
__global__ __launch_bounds__(256) void k5_au(const float* __restrict__ feats,
    const float* __restrict__ gw, const float* __restrict__ gb,
    float* __restrict__ a, float* __restrict__ u) {
  __shared__ float sf[32][97];
  __shared__ float swc[64 * C2];
  int b = blockIdx.y, n0 = blockIdx.x * 32;
  int tid = threadIdx.x;
  for (int i = tid; i < 32 * CHN; i += 256) {
    int nn = i / CHN, c = i - nn * CHN;
    sf[nn][c] = feats[((size_t)b * NP + n0 + nn) * CHN + c];
  }
  int nn = tid & 31, sub = tid >> 5;
  for (int oc = 0; oc < 3; ++oc) {
    __syncthreads();
    for (int i = tid; i < 64 * C2; i += 256) swc[i] = gw[(size_t)(oc * 64) * C2 + i];
    __syncthreads();
    float accA[8], accU[8];
#pragma unroll
    for (int j = 0; j < 8; ++j) { accA[j] = 0.f; accU[j] = 0.f; }
    for (int c = 0; c < CHN; ++c) {
      float f = sf[nn][c];
#pragma unroll
      for (int j = 0; j < 8; ++j) {
        float w1 = swc[(sub * 8 + j) * C2 + c];
        float wv2 = swc[(sub * 8 + j) * C2 + 96 + c];
        accA[j] = fmaf(w1 - wv2, f, accA[j]);
        accU[j] = fmaf(wv2, f, accU[j]);
      }
    }
    size_t row = ((size_t)b * NP + n0 + nn) * C2;
#pragma unroll
    for (int j = 0; j < 8; ++j) {
      int o = oc * 64 + sub * 8 + j;
      a[row + o] = accA[j] + gb[o];
      u[row + o] = accU[j];
    }
  }
}

// ---------- K6: agg = relu(a + max_k u[idx_k]); ol = fc2_w·agg + fc2_b
__global__ __launch_bounds__(256) void k6_edge(const float* __restrict__ a,
    const float* __restrict__ u, const int* __restrict__ nidx,
    const float* __restrict__ w2, const float* __restrict__ b2, float* __restrict__ ol) {
  __shared__ float sagg[32][193];
  int b = blockIdx.y, n0 = blockIdx.x * 32;
  int tid = threadIdx.x;
  int wv = tid >> 6, ln = tid & 63;
  for (int p = 0; p < 8; ++p) {
    int nn = wv * 8 + p;
    size_t row = (size_t)b * NP + n0 + nn;
    const int* ip = nidx + row * KNN;
    int idx[KNN];
#pragma unroll
    for (int k = 0; k < KNN; ++k) idx[k] = ip[k];
#pragma unroll
    for (int oo = 0; oo < 3; ++oo) {
      int o = oo * 64 + ln;
      float umax = -FLT_MAX;
#pragma unroll
      for (int k = 0; k < KNN; ++k)
        umax = fmaxf(umax, u[((size_t)b * NP + idx[k]) * C2 + o]);
      float av = a[row * C2 + o];
      sagg[nn][o] = fmaxf(av + umax, 0.f);
    }
  }
  __syncthreads();
  int nn = tid & 31, sub = tid >> 5;
  for (int j = 0; j < 12; ++j) {
    int o2 = sub + 8 * j;
    float acc = b2[o2];
    for (int o = 0; o < C2; ++o) acc = fmaf(w2[o2 * C2 + o], sagg[nn][o], acc);
    ol[((size_t)b * CHN + o2) * NP + n0 + nn] = acc;
  }
}

// ---------- K8: out = (ol - mean)*rstd + shortcut
__global__ __launch_bounds__(256) void k8_final(const float* __restrict__ ol,
    const float* __restrict__ stat, const float* __restrict__ x, float* __restrict__ out) {
  int i = blockIdx.x * 256 + threadIdx.x;
  int bo = i / NP;
  float m = stat[bo * 2], r = stat[bo * 2 + 1];
  out[i] = fmaf(ol[i] - m, r, x[i]);
}

extern "C" void kernel_launch(void* const* d_in, const int* in_sizes, int n_in,
                              void* d_out, int out_size, void* d_ws, size_t ws_size,
                              hipStream_t stream) {
  const float* x   = (const float*)d_in[0];
  const float* f1w = (const float*)d_in[1];
  const float* f1b = (const float*)d_in[2];
  const float* gw  = (const float*)d_in[3];
  const float* gb  = (const float*)d_in[4];
  const float* f2w = (const float*)d_in[5];
  const float* f2b = (const float*)d_in[6];
  float* out = (float*)d_out;
  char* ws = (char*)d_ws;

  constexpr size_t SZ_MAT = (size_t)BQ * CHN * NP * 4;           // 9,633,792
  constexpr size_t SZ_STR = (size_t)BQ * NT * NFRAG * 512 * 2;   // 14,450,688
  constexpr size_t SZ_PL  = (size_t)BQ * NLIST * NP * KNN * 4;   // 14,450,688
  constexpr size_t OFF_H   = 0;
  constexpr size_t OFF_PD  = 0;
  constexpr size_t OFF_PI  = OFF_PD + SZ_PL;
  constexpr size_t OFF_A   = 0;
  constexpr size_t OFF_AST = 2 * SZ_PL;
  constexpr size_t OFF_BST = OFF_AST + SZ_STR;
  constexpr size_t OFF_U   = OFF_AST;
  constexpr size_t OFF_NRM = OFF_AST + 2 * SZ_STR;
  constexpr size_t OFF_OL  = OFF_NRM;
  constexpr size_t OFF_FE  = OFF_NRM + SZ_MAT;
  constexpr size_t OFF_SQ  = OFF_FE + SZ_MAT;
  constexpr size_t OFF_ST1 = OFF_SQ + (size_t)BQ * NP * 4;
  constexpr size_t OFF_ST2 = OFF_ST1 + (size_t)BQ * CHN * 2 * 4;
  constexpr size_t OFF_NI  = OFF_ST2 + (size_t)BQ * CHN * 2 * 4;

  float* h   = (float*)(ws + OFF_H);
  float* fe  = (float*)(ws + OFF_FE);
  float* nrm = (float*)(ws + OFF_NRM);
  float* sq  = (float*)(ws + OFF_SQ);
  float* st1 = (float*)(ws + OFF_ST1);
  float* st2 = (float*)(ws + OFF_ST2);
  int*   ni  = (int*)(ws + OFF_NI);
  ushort* ast = (ushort*)(ws + OFF_AST);
  ushort* bst = (ushort*)(ws + OFF_BST);
  float* pd  = (float*)(ws + OFF_PD);
  int*   pi  = (int*)(ws + OFF_PI);
  float* aA  = (float*)(ws + OFF_A);
  float* uU  = (float*)(ws + OFF_U);
  float* ol  = (float*)(ws + OFF_OL);

  k1_conv1<<<dim3(NP / 64, BQ), 256, 0, stream>>>(x, f1w, f1b, h);
  k2_stats<<<dim3(BQ * CHN), 256, 0, stream>>>(h, st1);
  k3_norm<<<dim3(NP / 32, BQ), 256, 0, stream>>>(h, st1, fe, nrm, sq);
  k3b_prep<<<dim3(NT, BQ), 256, 0, stream>>>(nrm, ast, bst);
  k4_mfma<<<dim3(NT / 4, MCH, BQ), 256, 0, stream>>>(ast, bst, sq, pd, pi);
  k4b_merge<<<dim3(BQ * NP / 64), 64, 0, stream>>>(pd, pi, ni);
  k5_au<<<dim3(NP / 32, BQ), 256, 0, stream>>>(fe, gw, gb, aA, uU);
  k6_edge<<<dim3(NP / 32, BQ), 256, 0, stream>>>(aA, uU, ni, f2w, f2b, ol);
  k2_stats<<<dim3(BQ * CHN), 256, 0, stream>>>(ol, st2);
  k8_final<<<dim3(BQ * CHN * NP / 256), 256, 0, stream>>>(ol, st2, x, out);
}